// Round 6
// baseline (1596.551 us; speedup 1.0000x reference)
//
#include <hip/hip_runtime.h>
#include <cstdint>
#include <cmath>

// Problem constants
static constexpr int V_  = 50000;
static constexpr int E_  = 300;
static constexpr int C_  = 128;
static constexpr int B_  = 128;
static constexpr int SC_ = 512;
static constexpr int SE_ = 64;
static constexpr int NCOL = 768;   // [fw_gate 256 | fw_cand 128 | bw_gate 256 | bw_cand 128]
static constexpr int KP  = 320;    // K padded to 10 x 32 for MFMA

// ws layout (float offsets)
static constexpr size_t OFF_PROJ  = 0;
static constexpr size_t SZ_PROJ   = (size_t)V_ * NCOL;
static constexpr size_t OFF_WXP   = OFF_PROJ + SZ_PROJ;
static constexpr size_t SZ_WXP    = (size_t)304 * NCOL;
static constexpr size_t OFF_UALL  = OFF_WXP + SZ_WXP;
static constexpr size_t SZ_UALL   = (size_t)C_ * NCOL;
static constexpr size_t OFF_BIAS  = OFF_UALL + SZ_UALL;
static constexpr size_t SZ_BIAS   = NCOL;
static constexpr size_t OFF_ST    = OFF_BIAS + SZ_BIAS;
static constexpr size_t SZ_ST_CTX = (size_t)B_ * SC_ * C_;
static constexpr size_t SZ_ST_END = (size_t)B_ * SE_ * C_;
static constexpr size_t SZ_ST     = 2*SZ_ST_CTX + 2*SZ_ST_END;    // 75.5 MB
static constexpr size_t OFF_FEATS = OFF_ST + SZ_ST;
static constexpr size_t SZ_FEATS  = (size_t)B_ * 512;
static constexpr size_t OFF_BT    = OFF_FEATS + SZ_FEATS;
// A_hi/A_lo (bf16) OVERLAP the states region (dead once gemm ends; recur
// zeroes its own tail rows so no global memset is needed).

typedef __attribute__((ext_vector_type(8))) short bf16x8;
typedef __attribute__((ext_vector_type(4))) float f32x4;

static __device__ __forceinline__ unsigned short f2bf_rne(float f) {
  unsigned u = __float_as_uint(f);
  unsigned r = u + 0x7fffu + ((u >> 16) & 1u);
  return (unsigned short)(r >> 16);
}

static __device__ __forceinline__ void gload_lds16(const short* g, short* l) {
  __builtin_amdgcn_global_load_lds(
      (const __attribute__((address_space(1))) void*)g,
      (__attribute__((address_space(3))) void*)l, 16, 0, 0);
}

// fast activations: __expf + v_rcp_f32 (~1e-6 rel err; logit threshold 7.4e-5)
static __device__ __forceinline__ float fast_sigmoid(float x) {
  return __builtin_amdgcn_rcpf(1.f + __expf(-x));
}
static __device__ __forceinline__ float fast_tanh(float x) {
  return fmaf(-2.f, __builtin_amdgcn_rcpf(__expf(2.f * x) + 1.f), 1.f);
}

// ---------------------------------------------------------------------------
// Pack: Wxp[304][768] fp32, Uall[128][768], bias[768]
// ---------------------------------------------------------------------------
__global__ void pack_kernel(const float* __restrict__ fw_gw, const float* __restrict__ fw_gb,
                            const float* __restrict__ fw_cw, const float* __restrict__ fw_cb,
                            const float* __restrict__ bw_gw, const float* __restrict__ bw_gb,
                            const float* __restrict__ bw_cw, const float* __restrict__ bw_cb,
                            float* __restrict__ ws) {
  int i = blockIdx.x * 256 + threadIdx.x;
  float* Wxp  = ws + OFF_WXP;
  float* Uall = ws + OFF_UALL;
  float* bias = ws + OFF_BIAS;
  if (i < 304 * NCOL) {
    int k = i / NCOL, c = i % NCOL;
    float v = 0.f;
    if (k < 300) {
      if (c < 256)      v = fw_gw[k*256 + c];
      else if (c < 384) v = fw_cw[k*128 + (c-256)];
      else if (c < 640) v = bw_gw[k*256 + (c-384)];
      else              v = bw_cw[k*128 + (c-640)];
    }
    Wxp[i] = v;
    return;
  }
  int j = i - 304 * NCOL;
  if (j >= 0 && j < 128 * NCOL) {
    int k = j / NCOL, c = j % NCOL;
    int kk = 300 + k;
    float v;
    if (c < 256)      v = fw_gw[kk*256 + c];
    else if (c < 384) v = fw_cw[kk*128 + (c-256)];
    else if (c < 640) v = bw_gw[kk*256 + (c-384)];
    else              v = bw_cw[kk*128 + (c-640)];
    Uall[j] = v;
    return;
  }
  int m = j - 128 * NCOL;
  if (m >= 0 && m < NCOL) {
    float v;
    if (m < 256)      v = fw_gb[m];
    else if (m < 384) v = fw_cb[m-256];
    else if (m < 640) v = bw_gb[m-384];
    else              v = bw_cb[m-640];
    bias[m] = v;
  }
}

__global__ void pack_bt(const float* __restrict__ Wxp, short* __restrict__ Bthi,
                        short* __restrict__ Btlo) {
  int i = blockIdx.x * 256 + threadIdx.x;
  if (i >= NCOL * KP) return;
  int k = i % KP, n = i / KP;
  float v = (k < 304) ? Wxp[(size_t)k * NCOL + n] : 0.f;
  unsigned short h = f2bf_rne(v);
  float hf = __uint_as_float((unsigned)h << 16);
  unsigned short lo = f2bf_rne(v - hf);
  Bthi[i] = (short)h;
  Btlo[i] = (short)lo;
}

__global__ void pack_emb(const float* __restrict__ emb, short* __restrict__ Ahi,
                         short* __restrict__ Alo) {
  size_t i = (size_t)blockIdx.x * 256 + threadIdx.x;
  if (i >= (size_t)V_ * KP) return;
  int k = (int)(i % KP);
  size_t row = i / KP;
  float v = (k < E_) ? emb[row * E_ + k] : 0.f;
  unsigned short h = f2bf_rne(v);
  float hf = __uint_as_float((unsigned)h << 16);
  unsigned short lo = f2bf_rne(v - hf);
  Ahi[i] = (short)h;
  Alo[i] = (short)lo;
}

// ---------------------------------------------------------------------------
// proj = emb @ Wxp via bf16x3 split MFMA (m97 structure)
// ---------------------------------------------------------------------------
__global__ __launch_bounds__(256) void gemm_mfma(
    const short* __restrict__ Ahi, const short* __restrict__ Alo,
    const short* __restrict__ Bthi, const short* __restrict__ Btlo,
    float* __restrict__ proj) {
  __shared__ short lds[16384];
  int tid = threadIdx.x, wid = tid >> 6, lane = tid & 63;
  int n0 = blockIdx.x * 128, m0 = blockIdx.y * 128;
  f32x4 acc[4][4] = {};

  int lr = lane >> 2, lc = lane & 3;
  int q0 = wid * 2, q1 = q0 + 1;
  int r0 = q0 * 16 + lr, r1 = q1 * 16 + lr;
  int am0 = m0 + r0; if (am0 > V_ - 1) am0 = V_ - 1;
  int am1 = m0 + r1; if (am1 > V_ - 1) am1 = V_ - 1;
  size_t gaOff0 = (size_t)am0 * KP + lc * 8;
  size_t gaOff1 = (size_t)am1 * KP + lc * 8;
  size_t gbOff0 = (size_t)(n0 + r0) * KP + lc * 8;
  size_t gbOff1 = (size_t)(n0 + r1) * KP + lc * 8;

  int quad = lane >> 4;
  int arow = (wid >> 1) * 64 + (lane & 15);
  int brow = (wid & 1) * 64 + (lane & 15);

  for (int k0 = 0; k0 < KP; k0 += 32) {
    gload_lds16(Ahi  + gaOff0 + k0, lds +         q0 * 512);
    gload_lds16(Ahi  + gaOff1 + k0, lds +         q1 * 512);
    gload_lds16(Alo  + gaOff0 + k0, lds +  4096 + q0 * 512);
    gload_lds16(Alo  + gaOff1 + k0, lds +  4096 + q1 * 512);
    gload_lds16(Bthi + gbOff0 + k0, lds +  8192 + q0 * 512);
    gload_lds16(Bthi + gbOff1 + k0, lds +  8192 + q1 * 512);
    gload_lds16(Btlo + gbOff0 + k0, lds + 12288 + q0 * 512);
    gload_lds16(Btlo + gbOff1 + k0, lds + 12288 + q1 * 512);
    __syncthreads();

    bf16x8 ah[4], al[4], bh[4], bl[4];
#pragma unroll
    for (int i = 0; i < 4; ++i) {
      ah[i] = *(bf16x8*)&lds[        (arow + i*16) * 32 + quad * 8];
      al[i] = *(bf16x8*)&lds[ 4096 + (arow + i*16) * 32 + quad * 8];
      bh[i] = *(bf16x8*)&lds[ 8192 + (brow + i*16) * 32 + quad * 8];
      bl[i] = *(bf16x8*)&lds[12288 + (brow + i*16) * 32 + quad * 8];
    }
#pragma unroll
    for (int i = 0; i < 4; ++i)
#pragma unroll
      for (int j = 0; j < 4; ++j) {
        acc[i][j] = __builtin_amdgcn_mfma_f32_16x16x32_bf16(ah[i], bh[j], acc[i][j], 0, 0, 0);
        acc[i][j] = __builtin_amdgcn_mfma_f32_16x16x32_bf16(ah[i], bl[j], acc[i][j], 0, 0, 0);
        acc[i][j] = __builtin_amdgcn_mfma_f32_16x16x32_bf16(al[i], bh[j], acc[i][j], 0, 0, 0);
      }
    __syncthreads();
  }

  int colb = n0 + (wid & 1) * 64 + (lane & 15);
  int rowb = m0 + (wid >> 1) * 64 + quad * 4;
#pragma unroll
  for (int i = 0; i < 4; ++i) {
    int rb = rowb + i * 16;
#pragma unroll
    for (int j = 0; j < 4; ++j) {
      int cc = colb + j * 16;
#pragma unroll
      for (int r = 0; r < 4; ++r) {
        int rr = rb + r;
        if (rr < V_) proj[(size_t)rr * NCOL + cc] = acc[i][j][r];
      }
    }
  }
}

// ---------------------------------------------------------------------------
// Recurrence v6: 512 threads = 8 waves; wave w owns k/h-slice [16w,16w+16).
// h lives in REGISTERS (replicated x4 per wave; shfl broadcast) — never LDS.
// Wave-aligned consume: wave w consumes r cols [16w,+16) and u cols
// [128+16w,+16), so r*h and u also stay in-wave. Only gate/cand partial sums
// (pg, pc) cross waves -> exactly 2 barriers + 2 LDS round-trips per step.
// u-partials stored at col+16 to de-conflict banks vs r-partials.
// Per-lane weights: 64 gate + 32 cand = 96 floats (fits 128-VGPR budget).
// ---------------------------------------------------------------------------
__global__ __attribute__((amdgpu_flat_work_group_size(512, 512),
                          amdgpu_waves_per_eu(4, 4)))
void recur_kernel(
    const int* __restrict__ ctx, const int* __restrict__ endseq,
    const int* __restrict__ ctx_len, const int* __restrict__ end_len,
    const float* __restrict__ proj, const float* __restrict__ Uall,
    const float* __restrict__ bias, float* __restrict__ states) {
  __shared__ __align__(16) float pg[8][288];  // gate partials (r:0..127, u:144..271)
  __shared__ __align__(16) float pc[8][132];  // cand partials

  int bid = blockIdx.x;
  int tid = threadIdx.x;
  const int* seq; int S, L, b, dir; float* stbase;
  if (bid < 256) {
    b = bid >> 1; dir = bid & 1;
    seq = ctx + b * SC_; S = SC_; L = ctx_len[b];
    stbase = states + (dir ? SZ_ST_CTX : 0) + (size_t)b * SC_ * C_;
  } else {
    int q = bid - 256; b = q >> 1; dir = q & 1;
    seq = endseq + b * SE_; S = SE_; L = end_len[b];
    stbase = states + 2*SZ_ST_CTX + (dir ? SZ_ST_END : 0) + (size_t)b * SE_ * C_;
  }
  int dirOff = dir ? 384 : 0;
  int w = tid >> 6, lane = tid & 63;
  int l15 = lane & 15;
  int hidx  = 16 * w + l15;                       // h col this lane replicates
  int gcol4 = 4 * lane;                           // gate cols [4l,4l+4) (0..255)
  int pgidx = (lane < 32) ? 4 * lane : 4 * lane + 16;  // padded storage base
  int ccol2 = 2 * lane;                           // cand cols [2l,2l+2)
  bool is_r = ((lane & 31) < 16);
  int scol  = is_r ? (16 * w + l15) : (128 + 16 * w + l15);  // consume gate col
  int sidx  = is_r ? (16 * w + l15) : (144 + 16 * w + l15);  // padded index

  // gate weights 16k x 4j (64 VGPRs); cand weights 16k x 2j (32 VGPRs)
  float wgt[16][4];
  float wct[16][2];
#pragma unroll
  for (int kk = 0; kk < 16; ++kk) {
    const float* up = Uall + (size_t)(16 * w + kk) * NCOL + dirOff;
    float4 g4 = *(const float4*)(up + gcol4);
    wgt[kk][0] = g4.x; wgt[kk][1] = g4.y; wgt[kk][2] = g4.z; wgt[kk][3] = g4.w;
    float2 c2 = *(const float2*)(up + 256 + ccol2);
    wct[kk][0] = c2.x; wct[kk][1] = c2.y;
  }
  float bias_g = bias[dirOff + scol];
  float bias_c = bias[dirOff + 256 + hidx];

  float h = 0.f;

  // prefetch step 0's x-projection
  int pos0 = dir ? (L - 1) : 0;
  const float* xr0 = proj + (size_t)seq[pos0] * NCOL + dirOff;
  float xg = xr0[scol];
  float xc = xr0[256 + hidx];

  for (int t = 0; t < L; ++t) {
    // prefetch next step (hidden behind compute)
    float xg_n = 0.f, xc_n = 0.f;
    if (t + 1 < L) {
      int pos_n = dir ? (L - 2 - t) : (t + 1);
      const float* xr = proj + (size_t)seq[pos_n] * NCOL + dirOff;
      xg_n = xr[scol];
      xc_n = xr[256 + hidx];
    }

    // S1: gate partials for k-slice [16w,+16), cols [4l,4l+4)
    float a0 = 0.f, a1 = 0.f, a2 = 0.f, a3 = 0.f;
#pragma unroll
    for (int k = 0; k < 16; ++k) {
      float hk = __shfl(h, k, 64);   // h[16w+k] (lanes 0..15 hold slice)
      a0 += hk * wgt[k][0]; a1 += hk * wgt[k][1];
      a2 += hk * wgt[k][2]; a3 += hk * wgt[k][3];
    }
    *(float4*)(&pg[w][pgidx]) = make_float4(a0, a1, a2, a3);
    __syncthreads();   // B1

    // S3: consume gate col scol (in-wave-aligned)
    float g = xg + bias_g;
#pragma unroll
    for (int w2 = 0; w2 < 8; ++w2) g += pg[w2][sidx];
    g = fast_sigmoid(g);

    // S4: r*h stays in-wave (lanes with is_r; h matches scol there)
    float rh = g * h;

    // S5: cand partials for k-slice, cols [2l,2l+2)
    float c0 = 0.f, c1 = 0.f;
#pragma unroll
    for (int k = 0; k < 16; ++k) {
      float rhk = __shfl(rh, k, 64);  // rh[16w+k] from lanes 0..15
      c0 += rhk * wct[k][0]; c1 += rhk * wct[k][1];
    }
    *(float2*)(&pc[w][ccol2]) = make_float2(c0, c1);
    __syncthreads();   // B2

    // S6: h' for col hidx (all 4 replicas compute identically)
    float cs = xc + bias_c;
#pragma unroll
    for (int w2 = 0; w2 < 8; ++w2) cs += pc[w2][hidx];
    float c = fast_tanh(cs);
    float u = __shfl(g, 16 + l15, 64);   // u col 128+16w+l15 from lanes 16..31
    float hn = u * h + (1.f - u) * c;
    h = hn;
    if (lane < 16) {
      int pos = dir ? (L - 1 - t) : t;
      stbase[(size_t)pos * C_ + hidx] = hn;
    }
    xg = xg_n; xc = xc_n;
  }

  // zero tail rows [L, S) — replaces the global memset of states
  for (int i = L * C_ + tid; i < S * C_; i += 512) stbase[i] = 0.f;
}

// ---------------------------------------------------------------------------
// Attention: one WG per (b, array); flash-style online softmax.
// ---------------------------------------------------------------------------
__global__ __launch_bounds__(256, 2) void attn_kernel(
    const float* __restrict__ states, const float* __restrict__ att_v,
    const float* __restrict__ att_w, const float* __restrict__ att_b,
    float* __restrict__ feats) {
  __shared__ __align__(16) float st_s[8][132];
  __shared__ __align__(16) float pgA[8][8][132];
  __shared__ float score_s[8];
  __shared__ float cm[128], cl[128], ca[128];

  int bid = blockIdx.x, tid = threadIdx.x;
  int b, dir, S, featOff; const float* stb;
  if (bid < 256) {
    b = bid >> 1; dir = bid & 1; S = SC_;
    stb = states + (dir ? SZ_ST_CTX : 0) + (size_t)b * SC_ * C_;
    featOff = dir * 128;
  } else {
    int q = bid - 256; b = q >> 1; dir = q & 1; S = SE_;
    stb = states + 2*SZ_ST_CTX + (dir ? SZ_ST_END : 0) + (size_t)b * SE_ * C_;
    featOff = 256 + dir * 128;
  }

  int kg = tid >> 5, jg = tid & 31;
  float wreg[16][4];
#pragma unroll
  for (int kk = 0; kk < 16; ++kk) {
    float4 wv = *(const float4*)(att_w + (size_t)(kg*16 + kk) * C_ + jg*4);
    wreg[kk][0]=wv.x; wreg[kk][1]=wv.y; wreg[kk][2]=wv.z; wreg[kk][3]=wv.w;
  }
  int d0 = jg * 4;
  float4 b4 = *(const float4*)(att_b + d0);
  float4 v4 = *(const float4*)(att_v + d0);
  int c = tid & 127, half = tid >> 7;

  float m = -1e30f, lsum = 0.f, acc = 0.f;

  for (int s0 = 0; s0 < S; s0 += 8) {
    __syncthreads();
    for (int lId = tid; lId < 1024; lId += 256) {
      int r = lId >> 7, k = lId & 127;
      st_s[r][k] = stb[(size_t)(s0 + r) * C_ + k];
    }
    __syncthreads();

    float pacc[8][4] = {};
#pragma unroll
    for (int r = 0; r < 8; ++r) {
      const float4* srow4 = (const float4*)(&st_s[r][0]);
#pragma unroll
      for (int q = 0; q < 4; ++q) {
        float4 sv = srow4[kg*4 + q];
        float se[4] = {sv.x, sv.y, sv.z, sv.w};
#pragma unroll
        for (int e = 0; e < 4; ++e)
#pragma unroll
          for (int jj = 0; jj < 4; ++jj)
            pacc[r][jj] += se[e] * wreg[q*4 + e][jj];
      }
    }
#pragma unroll
    for (int r = 0; r < 8; ++r)
      *(float4*)(&pgA[kg][r][jg*4]) =
          make_float4(pacc[r][0], pacc[r][1], pacc[r][2], pacc[r][3]);
    __syncthreads();

    float4 p4 = make_float4(0.f, 0.f, 0.f, 0.f);
#pragma unroll
    for (int k2 = 0; k2 < 8; ++k2) {
      float4 t4 = *(const float4*)(&pgA[k2][kg][d0]);
      p4.x += t4.x; p4.y += t4.y; p4.z += t4.z; p4.w += t4.w;
    }
    float sc = tanhf(p4.x + b4.x) * v4.x + tanhf(p4.y + b4.y) * v4.y +
               tanhf(p4.z + b4.z) * v4.z + tanhf(p4.w + b4.w) * v4.w;
#pragma unroll
    for (int off = 16; off > 0; off >>= 1) sc += __shfl_xor(sc, off, 64);
    if (jg == 0) score_s[kg] = sc;
    __syncthreads();

    float srow[8]; float smax = m;
#pragma unroll
    for (int r = 0; r < 8; ++r) { srow[r] = score_s[r]; smax = fmaxf(smax, srow[r]); }
    float scale = expf(m - smax);
    acc *= scale; lsum *= scale; m = smax;
#pragma unroll
    for (int rr = 0; rr < 4; ++rr) {
      int r = half * 4 + rr;
      float w = expf(srow[r] - m);
      lsum += w;
      acc += w * st_s[r][c];
    }
  }

  __syncthreads();
  if (half == 1) { cm[c] = m; cl[c] = lsum; ca[c] = acc; }
  __syncthreads();
  if (half == 0) {
    float m1 = cm[c], l1 = cl[c], a1 = ca[c];
    float M = fmaxf(m, m1);
    float w0 = expf(m - M), w1 = expf(m1 - M);
    feats[b * 512 + featOff + c] = (acc * w0 + a1 * w1) / (lsum * w0 + l1 * w1);
  }
}

// ---------------------------------------------------------------------------
// Head
// ---------------------------------------------------------------------------
__global__ __launch_bounds__(128) void head_kernel(
    const float* __restrict__ feats, const float* __restrict__ hid_w,
    const float* __restrict__ hid_b, const float* __restrict__ out_w,
    const float* __restrict__ out_b, float* __restrict__ out) {
  __shared__ __align__(16) float f_s[512];
  __shared__ float part[2];
  int b = blockIdx.x, tid = threadIdx.x;
  for (int i = tid; i < 512; i += 128) f_s[i] = feats[b * 512 + i];
  __syncthreads();
  float h = hid_b[tid];
  for (int k = 0; k < 512; ++k) h += f_s[k] * hid_w[k * 128 + tid];
  h = fmaxf(h, 0.f);
  float p = h * out_w[tid];
#pragma unroll
  for (int off = 32; off > 0; off >>= 1) p += __shfl_xor(p, off, 64);
  if ((tid & 63) == 0) part[tid >> 6] = p;
  __syncthreads();
  if (tid == 0) out[b] = part[0] + part[1] + out_b[0];
}

// ---------------------------------------------------------------------------
extern "C" void kernel_launch(void* const* d_in, const int* in_sizes, int n_in,
                              void* d_out, int out_size, void* d_ws, size_t ws_size,
                              hipStream_t stream) {
  const int*   ctx     = (const int*)d_in[0];
  const int*   endseq  = (const int*)d_in[1];
  const int*   ctx_len = (const int*)d_in[2];
  const int*   end_len = (const int*)d_in[3];
  const float* emb     = (const float*)d_in[4];
  const float* fw_gw   = (const float*)d_in[5];
  const float* fw_gb   = (const float*)d_in[6];
  const float* fw_cw   = (const float*)d_in[7];
  const float* fw_cb   = (const float*)d_in[8];
  const float* bw_gw   = (const float*)d_in[9];
  const float* bw_gb   = (const float*)d_in[10];
  const float* bw_cw   = (const float*)d_in[11];
  const float* bw_cb   = (const float*)d_in[12];
  const float* att_v   = (const float*)d_in[13];
  const float* att_w   = (const float*)d_in[14];
  const float* att_b   = (const float*)d_in[15];
  const float* hid_w   = (const float*)d_in[16];
  const float* hid_b   = (const float*)d_in[17];
  const float* out_w   = (const float*)d_in[18];
  const float* out_b   = (const float*)d_in[19];
  float* ws  = (float*)d_ws;
  float* out = (float*)d_out;

  short* Ahi  = (short*)(ws + OFF_ST);
  short* Alo  = Ahi + (size_t)V_ * KP;
  short* Bthi = (short*)(ws + OFF_BT);
  short* Btlo = Bthi + (size_t)NCOL * KP;

  pack_kernel<<<1299, 256, 0, stream>>>(fw_gw, fw_gb, fw_cw, fw_cb,
                                        bw_gw, bw_gb, bw_cw, bw_cb, ws);
  pack_bt<<<(NCOL * KP + 255) / 256, 256, 0, stream>>>(ws + OFF_WXP, Bthi, Btlo);
  pack_emb<<<(int)(((size_t)V_ * KP + 255) / 256), 256, 0, stream>>>(emb, Ahi, Alo);

  dim3 ggrid(6, 391);
  gemm_mfma<<<ggrid, 256, 0, stream>>>(Ahi, Alo, Bthi, Btlo, ws + OFF_PROJ);

  recur_kernel<<<512, 512, 0, stream>>>(ctx, endseq, ctx_len, end_len,
                                        ws + OFF_PROJ, ws + OFF_UALL,
                                        ws + OFF_BIAS, ws + OFF_ST);

  attn_kernel<<<512, 256, 0, stream>>>(ws + OFF_ST, att_v, att_w, att_b,
                                       ws + OFF_FEATS);

  head_kernel<<<128, 128, 0, stream>>>(ws + OFF_FEATS, hid_w, hid_b,
                                       out_w, out_b, out);
}

// Round 7
// 1151.118 us; speedup vs baseline: 1.3870x; 1.3870x over previous
//
#include <hip/hip_runtime.h>
#include <cstdint>
#include <cmath>

// Problem constants
static constexpr int V_  = 50000;
static constexpr int E_  = 300;
static constexpr int C_  = 128;
static constexpr int B_  = 128;
static constexpr int SC_ = 512;
static constexpr int SE_ = 64;
static constexpr int NCOL = 768;   // [fw_gate 256 | fw_cand 128 | bw_gate 256 | bw_cand 128]
static constexpr int KP  = 320;    // K padded to 10 x 32 for MFMA

// ws layout (float offsets)
static constexpr size_t OFF_PROJ  = 0;
static constexpr size_t SZ_PROJ   = (size_t)V_ * NCOL;
static constexpr size_t OFF_WXP   = OFF_PROJ + SZ_PROJ;
static constexpr size_t SZ_WXP    = (size_t)304 * NCOL;
static constexpr size_t OFF_UALL  = OFF_WXP + SZ_WXP;
static constexpr size_t SZ_UALL   = (size_t)C_ * NCOL;
static constexpr size_t OFF_BIAS  = OFF_UALL + SZ_UALL;
static constexpr size_t SZ_BIAS   = NCOL;
static constexpr size_t OFF_ST    = OFF_BIAS + SZ_BIAS;
static constexpr size_t SZ_ST_CTX = (size_t)B_ * SC_ * C_;
static constexpr size_t SZ_ST_END = (size_t)B_ * SE_ * C_;
static constexpr size_t SZ_ST     = 2*SZ_ST_CTX + 2*SZ_ST_END;    // 75.5 MB
static constexpr size_t OFF_FEATS = OFF_ST + SZ_ST;
static constexpr size_t SZ_FEATS  = (size_t)B_ * 512;
static constexpr size_t OFF_BT    = OFF_FEATS + SZ_FEATS;
// A_hi/A_lo (bf16) OVERLAP the states region (dead once gemm ends; recur
// zeroes its own tail rows so no global memset is needed).

typedef __attribute__((ext_vector_type(8))) short bf16x8;
typedef __attribute__((ext_vector_type(4))) float f32x4;

static __device__ __forceinline__ unsigned short f2bf_rne(float f) {
  unsigned u = __float_as_uint(f);
  unsigned r = u + 0x7fffu + ((u >> 16) & 1u);
  return (unsigned short)(r >> 16);
}

static __device__ __forceinline__ void gload_lds16(const short* g, short* l) {
  __builtin_amdgcn_global_load_lds(
      (const __attribute__((address_space(1))) void*)g,
      (__attribute__((address_space(3))) void*)l, 16, 0, 0);
}

// fast activations: __expf + v_rcp_f32 (~1e-6 rel err; logit threshold 7.4e-5)
static __device__ __forceinline__ float fast_sigmoid(float x) {
  return __builtin_amdgcn_rcpf(1.f + __expf(-x));
}
static __device__ __forceinline__ float fast_tanh(float x) {
  return fmaf(-2.f, __builtin_amdgcn_rcpf(__expf(2.f * x) + 1.f), 1.f);
}

// ---------------------------------------------------------------------------
// Pack: Wxp[304][768] fp32, Uall[128][768], bias[768]
// ---------------------------------------------------------------------------
__global__ void pack_kernel(const float* __restrict__ fw_gw, const float* __restrict__ fw_gb,
                            const float* __restrict__ fw_cw, const float* __restrict__ fw_cb,
                            const float* __restrict__ bw_gw, const float* __restrict__ bw_gb,
                            const float* __restrict__ bw_cw, const float* __restrict__ bw_cb,
                            float* __restrict__ ws) {
  int i = blockIdx.x * 256 + threadIdx.x;
  float* Wxp  = ws + OFF_WXP;
  float* Uall = ws + OFF_UALL;
  float* bias = ws + OFF_BIAS;
  if (i < 304 * NCOL) {
    int k = i / NCOL, c = i % NCOL;
    float v = 0.f;
    if (k < 300) {
      if (c < 256)      v = fw_gw[k*256 + c];
      else if (c < 384) v = fw_cw[k*128 + (c-256)];
      else if (c < 640) v = bw_gw[k*256 + (c-384)];
      else              v = bw_cw[k*128 + (c-640)];
    }
    Wxp[i] = v;
    return;
  }
  int j = i - 304 * NCOL;
  if (j >= 0 && j < 128 * NCOL) {
    int k = j / NCOL, c = j % NCOL;
    int kk = 300 + k;
    float v;
    if (c < 256)      v = fw_gw[kk*256 + c];
    else if (c < 384) v = fw_cw[kk*128 + (c-256)];
    else if (c < 640) v = bw_gw[kk*256 + (c-384)];
    else              v = bw_cw[kk*128 + (c-640)];
    Uall[j] = v;
    return;
  }
  int m = j - 128 * NCOL;
  if (m >= 0 && m < NCOL) {
    float v;
    if (m < 256)      v = fw_gb[m];
    else if (m < 384) v = fw_cb[m-256];
    else if (m < 640) v = bw_gb[m-384];
    else              v = bw_cb[m-640];
    bias[m] = v;
  }
}

__global__ void pack_bt(const float* __restrict__ Wxp, short* __restrict__ Bthi,
                        short* __restrict__ Btlo) {
  int i = blockIdx.x * 256 + threadIdx.x;
  if (i >= NCOL * KP) return;
  int k = i % KP, n = i / KP;
  float v = (k < 304) ? Wxp[(size_t)k * NCOL + n] : 0.f;
  unsigned short h = f2bf_rne(v);
  float hf = __uint_as_float((unsigned)h << 16);
  unsigned short lo = f2bf_rne(v - hf);
  Bthi[i] = (short)h;
  Btlo[i] = (short)lo;
}

__global__ void pack_emb(const float* __restrict__ emb, short* __restrict__ Ahi,
                         short* __restrict__ Alo) {
  size_t i = (size_t)blockIdx.x * 256 + threadIdx.x;
  if (i >= (size_t)V_ * KP) return;
  int k = (int)(i % KP);
  size_t row = i / KP;
  float v = (k < E_) ? emb[row * E_ + k] : 0.f;
  unsigned short h = f2bf_rne(v);
  float hf = __uint_as_float((unsigned)h << 16);
  unsigned short lo = f2bf_rne(v - hf);
  Ahi[i] = (short)h;
  Alo[i] = (short)lo;
}

// ---------------------------------------------------------------------------
// proj = emb @ Wxp via bf16x3 split MFMA (m97 structure)
// ---------------------------------------------------------------------------
__global__ __launch_bounds__(256) void gemm_mfma(
    const short* __restrict__ Ahi, const short* __restrict__ Alo,
    const short* __restrict__ Bthi, const short* __restrict__ Btlo,
    float* __restrict__ proj) {
  __shared__ short lds[16384];
  int tid = threadIdx.x, wid = tid >> 6, lane = tid & 63;
  int n0 = blockIdx.x * 128, m0 = blockIdx.y * 128;
  f32x4 acc[4][4] = {};

  int lr = lane >> 2, lc = lane & 3;
  int q0 = wid * 2, q1 = q0 + 1;
  int r0 = q0 * 16 + lr, r1 = q1 * 16 + lr;
  int am0 = m0 + r0; if (am0 > V_ - 1) am0 = V_ - 1;
  int am1 = m0 + r1; if (am1 > V_ - 1) am1 = V_ - 1;
  size_t gaOff0 = (size_t)am0 * KP + lc * 8;
  size_t gaOff1 = (size_t)am1 * KP + lc * 8;
  size_t gbOff0 = (size_t)(n0 + r0) * KP + lc * 8;
  size_t gbOff1 = (size_t)(n0 + r1) * KP + lc * 8;

  int quad = lane >> 4;
  int arow = (wid >> 1) * 64 + (lane & 15);
  int brow = (wid & 1) * 64 + (lane & 15);

  for (int k0 = 0; k0 < KP; k0 += 32) {
    gload_lds16(Ahi  + gaOff0 + k0, lds +         q0 * 512);
    gload_lds16(Ahi  + gaOff1 + k0, lds +         q1 * 512);
    gload_lds16(Alo  + gaOff0 + k0, lds +  4096 + q0 * 512);
    gload_lds16(Alo  + gaOff1 + k0, lds +  4096 + q1 * 512);
    gload_lds16(Bthi + gbOff0 + k0, lds +  8192 + q0 * 512);
    gload_lds16(Bthi + gbOff1 + k0, lds +  8192 + q1 * 512);
    gload_lds16(Btlo + gbOff0 + k0, lds + 12288 + q0 * 512);
    gload_lds16(Btlo + gbOff1 + k0, lds + 12288 + q1 * 512);
    __syncthreads();

    bf16x8 ah[4], al[4], bh[4], bl[4];
#pragma unroll
    for (int i = 0; i < 4; ++i) {
      ah[i] = *(bf16x8*)&lds[        (arow + i*16) * 32 + quad * 8];
      al[i] = *(bf16x8*)&lds[ 4096 + (arow + i*16) * 32 + quad * 8];
      bh[i] = *(bf16x8*)&lds[ 8192 + (brow + i*16) * 32 + quad * 8];
      bl[i] = *(bf16x8*)&lds[12288 + (brow + i*16) * 32 + quad * 8];
    }
#pragma unroll
    for (int i = 0; i < 4; ++i)
#pragma unroll
      for (int j = 0; j < 4; ++j) {
        acc[i][j] = __builtin_amdgcn_mfma_f32_16x16x32_bf16(ah[i], bh[j], acc[i][j], 0, 0, 0);
        acc[i][j] = __builtin_amdgcn_mfma_f32_16x16x32_bf16(ah[i], bl[j], acc[i][j], 0, 0, 0);
        acc[i][j] = __builtin_amdgcn_mfma_f32_16x16x32_bf16(al[i], bh[j], acc[i][j], 0, 0, 0);
      }
    __syncthreads();
  }

  int colb = n0 + (wid & 1) * 64 + (lane & 15);
  int rowb = m0 + (wid >> 1) * 64 + quad * 4;
#pragma unroll
  for (int i = 0; i < 4; ++i) {
    int rb = rowb + i * 16;
#pragma unroll
    for (int j = 0; j < 4; ++j) {
      int cc = colb + j * 16;
#pragma unroll
      for (int r = 0; r < 4; ++r) {
        int rr = rb + r;
        if (rr < V_) proj[(size_t)rr * NCOL + cc] = acc[i][j][r];
      }
    }
  }
}

// ---------------------------------------------------------------------------
// Recurrence v7: WG=256 (4 waves), waves_per_eu(2,2) — the RA regime PROVEN
// (round 5) to keep 192 weight floats/lane resident. v6's 2-barrier dataflow:
// wave w owns k-slice [32w,32w+32); lane k<32 holds h[32w+k] in a register
// (replicated in lanes 32-63); h broadcast via shfl (never LDS). Wave-aligned
// consume: wave w's lanes consume r cols [32w,+32) (lanes 0-31) and u cols
// [128+32w,+32) (lanes 32-63), so r*h, u, and the h-update stay in-wave.
// Only pg/pc partial sums cross waves -> exactly 2 barriers per step.
// ---------------------------------------------------------------------------
__global__ __attribute__((amdgpu_flat_work_group_size(256, 256),
                          amdgpu_waves_per_eu(2, 2)))
void recur_kernel(
    const int* __restrict__ ctx, const int* __restrict__ endseq,
    const int* __restrict__ ctx_len, const int* __restrict__ end_len,
    const float* __restrict__ proj, const float* __restrict__ Uall,
    const float* __restrict__ bias, float* __restrict__ states) {
  __shared__ __align__(16) float pg[4][264];  // gate partials (256 cols + pad)
  __shared__ __align__(16) float pc[4][132];  // cand partials (128 cols + pad)

  int bid = blockIdx.x;
  int tid = threadIdx.x;
  const int* seq; int S, L, b, dir; float* stbase;
  if (bid < 256) {
    b = bid >> 1; dir = bid & 1;
    seq = ctx + b * SC_; S = SC_; L = ctx_len[b];
    stbase = states + (dir ? SZ_ST_CTX : 0) + (size_t)b * SC_ * C_;
  } else {
    int q = bid - 256; b = q >> 1; dir = q & 1;
    seq = endseq + b * SE_; S = SE_; L = end_len[b];
    stbase = states + 2*SZ_ST_CTX + (dir ? SZ_ST_END : 0) + (size_t)b * SE_ * C_;
  }
  int dirOff = dir ? 384 : 0;
  int w = tid >> 6, lane = tid & 63;
  int l31 = lane & 31;
  int hcol = 32 * w + l31;                       // h col this lane replicates
  bool is_r = (lane < 32);
  int scol = is_r ? hcol : (128 + hcol);         // gate col this lane consumes

  // gate weights 32k x 4j (128 VGPRs): cols [4*lane, 4*lane+4)
  // cand weights 32k x 2j (64 VGPRs):  cols [2*lane, 2*lane+2)
  float wgt[32][4];
  float wct[32][2];
#pragma unroll
  for (int kk = 0; kk < 32; ++kk) {
    const float* up = Uall + (size_t)(32 * w + kk) * NCOL + dirOff;
    float4 g4 = *(const float4*)(up + 4 * lane);
    wgt[kk][0] = g4.x; wgt[kk][1] = g4.y; wgt[kk][2] = g4.z; wgt[kk][3] = g4.w;
    float2 c2 = *(const float2*)(up + 256 + 2 * lane);
    wct[kk][0] = c2.x; wct[kk][1] = c2.y;
  }
  float bias_g = bias[dirOff + scol];
  float bias_c = bias[dirOff + 256 + hcol];

  float h = 0.f;   // h[hcol], replicated across the two half-waves

  // prefetch step 0's x-projection
  int pos0 = dir ? (L - 1) : 0;
  const float* xr0 = proj + (size_t)seq[pos0] * NCOL + dirOff;
  float xg = xr0[scol];
  float xc = xr0[256 + hcol];

  for (int t = 0; t < L; ++t) {
    // prefetch next step (hidden behind compute)
    float xg_n = 0.f, xc_n = 0.f;
    if (t + 1 < L) {
      int pos_n = dir ? (L - 2 - t) : (t + 1);
      const float* xr = proj + (size_t)seq[pos_n] * NCOL + dirOff;
      xg_n = xr[scol];
      xc_n = xr[256 + hcol];
    }

    // S1: gate partials for k-slice [32w,+32), cols [4*lane,+4)
    float a0 = 0.f, a1 = 0.f, a2 = 0.f, a3 = 0.f;
#pragma unroll
    for (int k = 0; k < 32; ++k) {
      float hk = __shfl(h, k, 64);   // h[32w+k] from lane k
      a0 += hk * wgt[k][0]; a1 += hk * wgt[k][1];
      a2 += hk * wgt[k][2]; a3 += hk * wgt[k][3];
    }
    *(float4*)(&pg[w][4 * lane]) = make_float4(a0, a1, a2, a3);
    __syncthreads();   // B1

    // S2a: consume gate col scol (wave-aligned; stride-1 reads, 2 lanes/bank)
    float g = xg + bias_g;
#pragma unroll
    for (int w2 = 0; w2 < 4; ++w2) g += pg[w2][scol];
    g = fast_sigmoid(g);
    float rh = g * h;   // valid where is_r (lanes 0-31); others unused

    // S2b: cand partials for k-slice, cols [2*lane,+2)
    float c0 = 0.f, c1 = 0.f;
#pragma unroll
    for (int k = 0; k < 32; ++k) {
      float rhk = __shfl(rh, k, 64);  // rh[32w+k] from lane k (<32)
      c0 += rhk * wct[k][0]; c1 += rhk * wct[k][1];
    }
    *(float2*)(&pc[w][2 * lane]) = make_float2(c0, c1);
    __syncthreads();   // B2

    // S3: h-update for col hcol (both half-waves compute identically)
    float cs = xc + bias_c;
#pragma unroll
    for (int w2 = 0; w2 < 4; ++w2) cs += pc[w2][hcol];
    float c = fast_tanh(cs);
    float u = __shfl(g, 32 + l31, 64);   // u[128+hcol] from lane 32+l31
    float hn = u * h + (1.f - u) * c;
    h = hn;
    if (is_r) {
      int pos = dir ? (L - 1 - t) : t;
      stbase[(size_t)pos * C_ + hcol] = hn;
    }
    xg = xg_n; xc = xc_n;
  }

  // zero tail rows [L, S) — replaces the global memset of states
  for (int i = L * C_ + tid; i < S * C_; i += 256) stbase[i] = 0.f;
}

// ---------------------------------------------------------------------------
// Attention: one WG per (b, array); flash-style online softmax.
// ---------------------------------------------------------------------------
__global__ __launch_bounds__(256, 2) void attn_kernel(
    const float* __restrict__ states, const float* __restrict__ att_v,
    const float* __restrict__ att_w, const float* __restrict__ att_b,
    float* __restrict__ feats) {
  __shared__ __align__(16) float st_s[8][132];
  __shared__ __align__(16) float pgA[8][8][132];
  __shared__ float score_s[8];
  __shared__ float cm[128], cl[128], ca[128];

  int bid = blockIdx.x, tid = threadIdx.x;
  int b, dir, S, featOff; const float* stb;
  if (bid < 256) {
    b = bid >> 1; dir = bid & 1; S = SC_;
    stb = states + (dir ? SZ_ST_CTX : 0) + (size_t)b * SC_ * C_;
    featOff = dir * 128;
  } else {
    int q = bid - 256; b = q >> 1; dir = q & 1; S = SE_;
    stb = states + 2*SZ_ST_CTX + (dir ? SZ_ST_END : 0) + (size_t)b * SE_ * C_;
    featOff = 256 + dir * 128;
  }

  int kg = tid >> 5, jg = tid & 31;
  float wreg[16][4];
#pragma unroll
  for (int kk = 0; kk < 16; ++kk) {
    float4 wv = *(const float4*)(att_w + (size_t)(kg*16 + kk) * C_ + jg*4);
    wreg[kk][0]=wv.x; wreg[kk][1]=wv.y; wreg[kk][2]=wv.z; wreg[kk][3]=wv.w;
  }
  int d0 = jg * 4;
  float4 b4 = *(const float4*)(att_b + d0);
  float4 v4 = *(const float4*)(att_v + d0);
  int c = tid & 127, half = tid >> 7;

  float m = -1e30f, lsum = 0.f, acc = 0.f;

  for (int s0 = 0; s0 < S; s0 += 8) {
    __syncthreads();
    for (int lId = tid; lId < 1024; lId += 256) {
      int r = lId >> 7, k = lId & 127;
      st_s[r][k] = stb[(size_t)(s0 + r) * C_ + k];
    }
    __syncthreads();

    float pacc[8][4] = {};
#pragma unroll
    for (int r = 0; r < 8; ++r) {
      const float4* srow4 = (const float4*)(&st_s[r][0]);
#pragma unroll
      for (int q = 0; q < 4; ++q) {
        float4 sv = srow4[kg*4 + q];
        float se[4] = {sv.x, sv.y, sv.z, sv.w};
#pragma unroll
        for (int e = 0; e < 4; ++e)
#pragma unroll
          for (int jj = 0; jj < 4; ++jj)
            pacc[r][jj] += se[e] * wreg[q*4 + e][jj];
      }
    }
#pragma unroll
    for (int r = 0; r < 8; ++r)
      *(float4*)(&pgA[kg][r][jg*4]) =
          make_float4(pacc[r][0], pacc[r][1], pacc[r][2], pacc[r][3]);
    __syncthreads();

    float4 p4 = make_float4(0.f, 0.f, 0.f, 0.f);
#pragma unroll
    for (int k2 = 0; k2 < 8; ++k2) {
      float4 t4 = *(const float4*)(&pgA[k2][kg][d0]);
      p4.x += t4.x; p4.y += t4.y; p4.z += t4.z; p4.w += t4.w;
    }
    float sc = tanhf(p4.x + b4.x) * v4.x + tanhf(p4.y + b4.y) * v4.y +
               tanhf(p4.z + b4.z) * v4.z + tanhf(p4.w + b4.w) * v4.w;
#pragma unroll
    for (int off = 16; off > 0; off >>= 1) sc += __shfl_xor(sc, off, 64);
    if (jg == 0) score_s[kg] = sc;
    __syncthreads();

    float srow[8]; float smax = m;
#pragma unroll
    for (int r = 0; r < 8; ++r) { srow[r] = score_s[r]; smax = fmaxf(smax, srow[r]); }
    float scale = expf(m - smax);
    acc *= scale; lsum *= scale; m = smax;
#pragma unroll
    for (int rr = 0; rr < 4; ++rr) {
      int r = half * 4 + rr;
      float w = expf(srow[r] - m);
      lsum += w;
      acc += w * st_s[r][c];
    }
  }

  __syncthreads();
  if (half == 1) { cm[c] = m; cl[c] = lsum; ca[c] = acc; }
  __syncthreads();
  if (half == 0) {
    float m1 = cm[c], l1 = cl[c], a1 = ca[c];
    float M = fmaxf(m, m1);
    float w0 = expf(m - M), w1 = expf(m1 - M);
    feats[b * 512 + featOff + c] = (acc * w0 + a1 * w1) / (lsum * w0 + l1 * w1);
  }
}

// ---------------------------------------------------------------------------
// Head
// ---------------------------------------------------------------------------
__global__ __launch_bounds__(128) void head_kernel(
    const float* __restrict__ feats, const float* __restrict__ hid_w,
    const float* __restrict__ hid_b, const float* __restrict__ out_w,
    const float* __restrict__ out_b, float* __restrict__ out) {
  __shared__ __align__(16) float f_s[512];
  __shared__ float part[2];
  int b = blockIdx.x, tid = threadIdx.x;
  for (int i = tid; i < 512; i += 128) f_s[i] = feats[b * 512 + i];
  __syncthreads();
  float h = hid_b[tid];
  for (int k = 0; k < 512; ++k) h += f_s[k] * hid_w[k * 128 + tid];
  h = fmaxf(h, 0.f);
  float p = h * out_w[tid];
#pragma unroll
  for (int off = 32; off > 0; off >>= 1) p += __shfl_xor(p, off, 64);
  if ((tid & 63) == 0) part[tid >> 6] = p;
  __syncthreads();
  if (tid == 0) out[b] = part[0] + part[1] + out_b[0];
}

// ---------------------------------------------------------------------------
extern "C" void kernel_launch(void* const* d_in, const int* in_sizes, int n_in,
                              void* d_out, int out_size, void* d_ws, size_t ws_size,
                              hipStream_t stream) {
  const int*   ctx     = (const int*)d_in[0];
  const int*   endseq  = (const int*)d_in[1];
  const int*   ctx_len = (const int*)d_in[2];
  const int*   end_len = (const int*)d_in[3];
  const float* emb     = (const float*)d_in[4];
  const float* fw_gw   = (const float*)d_in[5];
  const float* fw_gb   = (const float*)d_in[6];
  const float* fw_cw   = (const float*)d_in[7];
  const float* fw_cb   = (const float*)d_in[8];
  const float* bw_gw   = (const float*)d_in[9];
  const float* bw_gb   = (const float*)d_in[10];
  const float* bw_cw   = (const float*)d_in[11];
  const float* bw_cb   = (const float*)d_in[12];
  const float* att_v   = (const float*)d_in[13];
  const float* att_w   = (const float*)d_in[14];
  const float* att_b   = (const float*)d_in[15];
  const float* hid_w   = (const float*)d_in[16];
  const float* hid_b   = (const float*)d_in[17];
  const float* out_w   = (const float*)d_in[18];
  const float* out_b   = (const float*)d_in[19];
  float* ws  = (float*)d_ws;
  float* out = (float*)d_out;

  short* Ahi  = (short*)(ws + OFF_ST);
  short* Alo  = Ahi + (size_t)V_ * KP;
  short* Bthi = (short*)(ws + OFF_BT);
  short* Btlo = Bthi + (size_t)NCOL * KP;

  pack_kernel<<<1299, 256, 0, stream>>>(fw_gw, fw_gb, fw_cw, fw_cb,
                                        bw_gw, bw_gb, bw_cw, bw_cb, ws);
  pack_bt<<<(NCOL * KP + 255) / 256, 256, 0, stream>>>(ws + OFF_WXP, Bthi, Btlo);
  pack_emb<<<(int)(((size_t)V_ * KP + 255) / 256), 256, 0, stream>>>(emb, Ahi, Alo);

  dim3 ggrid(6, 391);
  gemm_mfma<<<ggrid, 256, 0, stream>>>(Ahi, Alo, Bthi, Btlo, ws + OFF_PROJ);

  recur_kernel<<<512, 256, 0, stream>>>(ctx, endseq, ctx_len, end_len,
                                        ws + OFF_PROJ, ws + OFF_UALL,
                                        ws + OFF_BIAS, ws + OFF_ST);

  attn_kernel<<<512, 256, 0, stream>>>(ws + OFF_ST, att_v, att_w, att_b,
                                       ws + OFF_FEATS);

  head_kernel<<<128, 128, 0, stream>>>(ws + OFF_FEATS, hid_w, hid_b,
                                       out_w, out_b, out);
}

// Round 8
// 988.593 us; speedup vs baseline: 1.6150x; 1.1644x over previous
//
#include <hip/hip_runtime.h>
#include <cstdint>
#include <cmath>

// Problem constants
static constexpr int V_  = 50000;
static constexpr int E_  = 300;
static constexpr int C_  = 128;
static constexpr int B_  = 128;
static constexpr int SC_ = 512;
static constexpr int SE_ = 64;
static constexpr int NCOL = 768;   // [fw_gate 256 | fw_cand 128 | bw_gate 256 | bw_cand 128]
static constexpr int KP  = 320;    // K padded to 10 x 32 for MFMA

// ws layout (float offsets)
static constexpr size_t OFF_PROJ  = 0;
static constexpr size_t SZ_PROJ   = (size_t)V_ * NCOL;
static constexpr size_t OFF_WXP   = OFF_PROJ + SZ_PROJ;
static constexpr size_t SZ_WXP    = (size_t)304 * NCOL;
static constexpr size_t OFF_UALL  = OFF_WXP + SZ_WXP;
static constexpr size_t SZ_UALL   = (size_t)C_ * NCOL;
static constexpr size_t OFF_BIAS  = OFF_UALL + SZ_UALL;
static constexpr size_t SZ_BIAS   = NCOL;
static constexpr size_t OFF_ST    = OFF_BIAS + SZ_BIAS;
static constexpr size_t SZ_ST_CTX = (size_t)B_ * SC_ * C_;
static constexpr size_t SZ_ST_END = (size_t)B_ * SE_ * C_;
static constexpr size_t SZ_ST     = 2*SZ_ST_CTX + 2*SZ_ST_END;    // 75.5 MB
static constexpr size_t OFF_FEATS = OFF_ST + SZ_ST;
static constexpr size_t SZ_FEATS  = (size_t)B_ * 512;
static constexpr size_t OFF_BT    = OFF_FEATS + SZ_FEATS;
// A_hi/A_lo (bf16) OVERLAP the states region (dead once gemm ends; recur
// zeroes its own tail rows so no global memset is needed).

typedef __attribute__((ext_vector_type(8))) short bf16x8;
typedef __attribute__((ext_vector_type(4))) float f32x4;

static __device__ __forceinline__ unsigned short f2bf_rne(float f) {
  unsigned u = __float_as_uint(f);
  unsigned r = u + 0x7fffu + ((u >> 16) & 1u);
  return (unsigned short)(r >> 16);
}

static __device__ __forceinline__ void gload_lds16(const short* g, short* l) {
  __builtin_amdgcn_global_load_lds(
      (const __attribute__((address_space(1))) void*)g,
      (__attribute__((address_space(3))) void*)l, 16, 0, 0);
}

// fast activations: __expf + v_rcp_f32 (~1e-6 rel err; logit threshold 7.4e-5)
static __device__ __forceinline__ float fast_sigmoid(float x) {
  return __builtin_amdgcn_rcpf(1.f + __expf(-x));
}
static __device__ __forceinline__ float fast_tanh(float x) {
  return fmaf(-2.f, __builtin_amdgcn_rcpf(__expf(2.f * x) + 1.f), 1.f);
}

// ---------------------------------------------------------------------------
// Pack: Wxp[304][768] fp32, Uall[128][768], bias[768]
// ---------------------------------------------------------------------------
__global__ void pack_kernel(const float* __restrict__ fw_gw, const float* __restrict__ fw_gb,
                            const float* __restrict__ fw_cw, const float* __restrict__ fw_cb,
                            const float* __restrict__ bw_gw, const float* __restrict__ bw_gb,
                            const float* __restrict__ bw_cw, const float* __restrict__ bw_cb,
                            float* __restrict__ ws) {
  int i = blockIdx.x * 256 + threadIdx.x;
  float* Wxp  = ws + OFF_WXP;
  float* Uall = ws + OFF_UALL;
  float* bias = ws + OFF_BIAS;
  if (i < 304 * NCOL) {
    int k = i / NCOL, c = i % NCOL;
    float v = 0.f;
    if (k < 300) {
      if (c < 256)      v = fw_gw[k*256 + c];
      else if (c < 384) v = fw_cw[k*128 + (c-256)];
      else if (c < 640) v = bw_gw[k*256 + (c-384)];
      else              v = bw_cw[k*128 + (c-640)];
    }
    Wxp[i] = v;
    return;
  }
  int j = i - 304 * NCOL;
  if (j >= 0 && j < 128 * NCOL) {
    int k = j / NCOL, c = j % NCOL;
    int kk = 300 + k;
    float v;
    if (c < 256)      v = fw_gw[kk*256 + c];
    else if (c < 384) v = fw_cw[kk*128 + (c-256)];
    else if (c < 640) v = bw_gw[kk*256 + (c-384)];
    else              v = bw_cw[kk*128 + (c-640)];
    Uall[j] = v;
    return;
  }
  int m = j - 128 * NCOL;
  if (m >= 0 && m < NCOL) {
    float v;
    if (m < 256)      v = fw_gb[m];
    else if (m < 384) v = fw_cb[m-256];
    else if (m < 640) v = bw_gb[m-384];
    else              v = bw_cb[m-640];
    bias[m] = v;
  }
}

__global__ void pack_bt(const float* __restrict__ Wxp, short* __restrict__ Bthi,
                        short* __restrict__ Btlo) {
  int i = blockIdx.x * 256 + threadIdx.x;
  if (i >= NCOL * KP) return;
  int k = i % KP, n = i / KP;
  float v = (k < 304) ? Wxp[(size_t)k * NCOL + n] : 0.f;
  unsigned short h = f2bf_rne(v);
  float hf = __uint_as_float((unsigned)h << 16);
  unsigned short lo = f2bf_rne(v - hf);
  Bthi[i] = (short)h;
  Btlo[i] = (short)lo;
}

__global__ void pack_emb(const float* __restrict__ emb, short* __restrict__ Ahi,
                         short* __restrict__ Alo) {
  size_t i = (size_t)blockIdx.x * 256 + threadIdx.x;
  if (i >= (size_t)V_ * KP) return;
  int k = (int)(i % KP);
  size_t row = i / KP;
  float v = (k < E_) ? emb[row * E_ + k] : 0.f;
  unsigned short h = f2bf_rne(v);
  float hf = __uint_as_float((unsigned)h << 16);
  unsigned short lo = f2bf_rne(v - hf);
  Ahi[i] = (short)h;
  Alo[i] = (short)lo;
}

// ---------------------------------------------------------------------------
// proj = emb @ Wxp via bf16x3 split MFMA (m97 structure)
// ---------------------------------------------------------------------------
__global__ __launch_bounds__(256) void gemm_mfma(
    const short* __restrict__ Ahi, const short* __restrict__ Alo,
    const short* __restrict__ Bthi, const short* __restrict__ Btlo,
    float* __restrict__ proj) {
  __shared__ short lds[16384];
  int tid = threadIdx.x, wid = tid >> 6, lane = tid & 63;
  int n0 = blockIdx.x * 128, m0 = blockIdx.y * 128;
  f32x4 acc[4][4] = {};

  int lr = lane >> 2, lc = lane & 3;
  int q0 = wid * 2, q1 = q0 + 1;
  int r0 = q0 * 16 + lr, r1 = q1 * 16 + lr;
  int am0 = m0 + r0; if (am0 > V_ - 1) am0 = V_ - 1;
  int am1 = m0 + r1; if (am1 > V_ - 1) am1 = V_ - 1;
  size_t gaOff0 = (size_t)am0 * KP + lc * 8;
  size_t gaOff1 = (size_t)am1 * KP + lc * 8;
  size_t gbOff0 = (size_t)(n0 + r0) * KP + lc * 8;
  size_t gbOff1 = (size_t)(n0 + r1) * KP + lc * 8;

  int quad = lane >> 4;
  int arow = (wid >> 1) * 64 + (lane & 15);
  int brow = (wid & 1) * 64 + (lane & 15);

  for (int k0 = 0; k0 < KP; k0 += 32) {
    gload_lds16(Ahi  + gaOff0 + k0, lds +         q0 * 512);
    gload_lds16(Ahi  + gaOff1 + k0, lds +         q1 * 512);
    gload_lds16(Alo  + gaOff0 + k0, lds +  4096 + q0 * 512);
    gload_lds16(Alo  + gaOff1 + k0, lds +  4096 + q1 * 512);
    gload_lds16(Bthi + gbOff0 + k0, lds +  8192 + q0 * 512);
    gload_lds16(Bthi + gbOff1 + k0, lds +  8192 + q1 * 512);
    gload_lds16(Btlo + gbOff0 + k0, lds + 12288 + q0 * 512);
    gload_lds16(Btlo + gbOff1 + k0, lds + 12288 + q1 * 512);
    __syncthreads();

    bf16x8 ah[4], al[4], bh[4], bl[4];
#pragma unroll
    for (int i = 0; i < 4; ++i) {
      ah[i] = *(bf16x8*)&lds[        (arow + i*16) * 32 + quad * 8];
      al[i] = *(bf16x8*)&lds[ 4096 + (arow + i*16) * 32 + quad * 8];
      bh[i] = *(bf16x8*)&lds[ 8192 + (brow + i*16) * 32 + quad * 8];
      bl[i] = *(bf16x8*)&lds[12288 + (brow + i*16) * 32 + quad * 8];
    }
#pragma unroll
    for (int i = 0; i < 4; ++i)
#pragma unroll
      for (int j = 0; j < 4; ++j) {
        acc[i][j] = __builtin_amdgcn_mfma_f32_16x16x32_bf16(ah[i], bh[j], acc[i][j], 0, 0, 0);
        acc[i][j] = __builtin_amdgcn_mfma_f32_16x16x32_bf16(ah[i], bl[j], acc[i][j], 0, 0, 0);
        acc[i][j] = __builtin_amdgcn_mfma_f32_16x16x32_bf16(al[i], bh[j], acc[i][j], 0, 0, 0);
      }
    __syncthreads();
  }

  int colb = n0 + (wid & 1) * 64 + (lane & 15);
  int rowb = m0 + (wid >> 1) * 64 + quad * 4;
#pragma unroll
  for (int i = 0; i < 4; ++i) {
    int rb = rowb + i * 16;
#pragma unroll
    for (int j = 0; j < 4; ++j) {
      int cc = colb + j * 16;
#pragma unroll
      for (int r = 0; r < 4; ++r) {
        int rr = rb + r;
        if (rr < V_) proj[(size_t)rr * NCOL + cc] = acc[i][j][r];
      }
    }
  }
}

// ---------------------------------------------------------------------------
// Recurrence v8: v7's 2-barrier wave-aligned dataflow + round-5's RA regime,
// with all bulk cross-lane broadcast via LDS ds_read_b128 (same-address
// broadcast is free) instead of shfl. h/rh slices are wave-private: same-wave
// ds_write -> ds_read needs only lgkmcnt ordering, NO barrier. Only pg/pc
// partial sums cross waves -> exactly 2 barriers per step.
// Wave w owns k/h-slice [32w,32w+32). Lanes 0-31: r cols + h/rh ownership;
// lanes 32-63: u cols. Weights: 128 gate + 64 cand floats/lane, resident in
// the unified VGPR/AGPR file at waves_per_eu(2,2) (proven round 5/7).
// ---------------------------------------------------------------------------
__global__ __attribute__((amdgpu_flat_work_group_size(256, 256),
                          amdgpu_waves_per_eu(2, 2)))
void recur_kernel(
    const int* __restrict__ ctx, const int* __restrict__ endseq,
    const int* __restrict__ ctx_len, const int* __restrict__ end_len,
    const float* __restrict__ proj, const float* __restrict__ Uall,
    const float* __restrict__ bias, float* __restrict__ states) {
  __shared__ __align__(16) float h_s[128];
  __shared__ __align__(16) float rh_s[128];
  __shared__ __align__(16) float pg[4][264];  // gate partials (256 cols + pad)
  __shared__ __align__(16) float pc[4][132];  // cand partials (128 cols + pad)

  int bid = blockIdx.x;
  int tid = threadIdx.x;
  const int* seq; int S, L, b, dir; float* stbase;
  if (bid < 256) {
    b = bid >> 1; dir = bid & 1;
    seq = ctx + b * SC_; S = SC_; L = ctx_len[b];
    stbase = states + (dir ? SZ_ST_CTX : 0) + (size_t)b * SC_ * C_;
  } else {
    int q = bid - 256; b = q >> 1; dir = q & 1;
    seq = endseq + b * SE_; S = SE_; L = end_len[b];
    stbase = states + 2*SZ_ST_CTX + (dir ? SZ_ST_END : 0) + (size_t)b * SE_ * C_;
  }
  int dirOff = dir ? 384 : 0;
  int w = tid >> 6, lane = tid & 63;
  int l31 = lane & 31;
  int hcol = 32 * w + l31;                 // h col this lane tracks (replicated)
  bool is_r = (lane < 32);
  int scol = is_r ? hcol : (128 + hcol);   // gate col this lane consumes

  // gate weights 32k x 4j (cols [4*lane,+4)); cand 32k x 2j (cols [2*lane,+2))
  float wgt[32][4];
  float wct[32][2];
#pragma unroll
  for (int kk = 0; kk < 32; ++kk) {
    const float* up = Uall + (size_t)(32 * w + kk) * NCOL + dirOff;
    float4 g4 = *(const float4*)(up + 4 * lane);
    wgt[kk][0] = g4.x; wgt[kk][1] = g4.y; wgt[kk][2] = g4.z; wgt[kk][3] = g4.w;
    float2 c2 = *(const float2*)(up + 256 + 2 * lane);
    wct[kk][0] = c2.x; wct[kk][1] = c2.y;
  }
  float bias_g = bias[dirOff + scol];
  float bias_c = bias[dirOff + 256 + hcol];

  float hreg = 0.f;                        // h[hcol] (register copy)
  if (tid < 128) h_s[tid] = 0.f;
  __syncthreads();

  // prefetch step 0's x-projection
  int pos0 = dir ? (L - 1) : 0;
  const float* xr0 = proj + (size_t)seq[pos0] * NCOL + dirOff;
  float xg = xr0[scol];
  float xc = xr0[256 + hcol];

  const float4* h4  = (const float4*)(h_s  + 32 * w);   // own slice
  const float4* rh4 = (const float4*)(rh_s + 32 * w);

  for (int t = 0; t < L; ++t) {
    // prefetch next step (hidden behind compute)
    float xg_n = 0.f, xc_n = 0.f;
    if (t + 1 < L) {
      int pos_n = dir ? (L - 2 - t) : (t + 1);
      const float* xr = proj + (size_t)seq[pos_n] * NCOL + dirOff;
      xg_n = xr[scol];
      xc_n = xr[256 + hcol];
    }

    // S1: gate partials for own k-slice via LDS broadcast reads (b128)
    float a0 = 0.f, a1 = 0.f, a2 = 0.f, a3 = 0.f;
#pragma unroll
    for (int q = 0; q < 8; ++q) {
      float4 hv = h4[q];
      float he[4] = {hv.x, hv.y, hv.z, hv.w};
#pragma unroll
      for (int e = 0; e < 4; ++e) {
        a0 += he[e] * wgt[q*4+e][0]; a1 += he[e] * wgt[q*4+e][1];
        a2 += he[e] * wgt[q*4+e][2]; a3 += he[e] * wgt[q*4+e][3];
      }
    }
    *(float4*)(&pg[w][4 * lane]) = make_float4(a0, a1, a2, a3);
    __syncthreads();   // B1

    // S2: consume gate col scol (wave-aligned)
    float g = xg + bias_g;
#pragma unroll
    for (int w2 = 0; w2 < 4; ++w2) g += pg[w2][scol];
    g = fast_sigmoid(g);
    if (is_r) rh_s[hcol] = g * hreg;   // same-wave write; lgkmcnt orders reads

    // cand partials via LDS broadcast reads of own rh slice
    float c0 = 0.f, c1 = 0.f;
#pragma unroll
    for (int q = 0; q < 8; ++q) {
      float4 rv = rh4[q];
      float re[4] = {rv.x, rv.y, rv.z, rv.w};
#pragma unroll
      for (int e = 0; e < 4; ++e) {
        c0 += re[e] * wct[q*4+e][0]; c1 += re[e] * wct[q*4+e][1];
      }
    }
    *(float2*)(&pc[w][2 * lane]) = make_float2(c0, c1);
    __syncthreads();   // B2

    // S3: h-update for col hcol (both half-waves compute identically)
    float cs = xc + bias_c;
#pragma unroll
    for (int w2 = 0; w2 < 4; ++w2) cs += pc[w2][hcol];
    float c = fast_tanh(cs);
    float u = __shfl(g, 32 + l31, 64);   // u[128+hcol] from lane 32+l31
    float hn = u * hreg + (1.f - u) * c;
    hreg = hn;
    if (is_r) {
      h_s[hcol] = hn;                    // own slice; next S1 read is same-wave
      int pos = dir ? (L - 1 - t) : t;
      stbase[(size_t)pos * C_ + hcol] = hn;
    }
    xg = xg_n; xc = xc_n;
  }

  // zero tail rows [L, S) — replaces the global memset of states
  for (int i = L * C_ + tid; i < S * C_; i += 256) stbase[i] = 0.f;
}

// ---------------------------------------------------------------------------
// Attention: one WG per (b, array); flash-style online softmax.
// ---------------------------------------------------------------------------
__global__ __launch_bounds__(256, 2) void attn_kernel(
    const float* __restrict__ states, const float* __restrict__ att_v,
    const float* __restrict__ att_w, const float* __restrict__ att_b,
    float* __restrict__ feats) {
  __shared__ __align__(16) float st_s[8][132];
  __shared__ __align__(16) float pgA[8][8][132];
  __shared__ float score_s[8];
  __shared__ float cm[128], cl[128], ca[128];

  int bid = blockIdx.x, tid = threadIdx.x;
  int b, dir, S, featOff; const float* stb;
  if (bid < 256) {
    b = bid >> 1; dir = bid & 1; S = SC_;
    stb = states + (dir ? SZ_ST_CTX : 0) + (size_t)b * SC_ * C_;
    featOff = dir * 128;
  } else {
    int q = bid - 256; b = q >> 1; dir = q & 1; S = SE_;
    stb = states + 2*SZ_ST_CTX + (dir ? SZ_ST_END : 0) + (size_t)b * SE_ * C_;
    featOff = 256 + dir * 128;
  }

  int kg = tid >> 5, jg = tid & 31;
  float wreg[16][4];
#pragma unroll
  for (int kk = 0; kk < 16; ++kk) {
    float4 wv = *(const float4*)(att_w + (size_t)(kg*16 + kk) * C_ + jg*4);
    wreg[kk][0]=wv.x; wreg[kk][1]=wv.y; wreg[kk][2]=wv.z; wreg[kk][3]=wv.w;
  }
  int d0 = jg * 4;
  float4 b4 = *(const float4*)(att_b + d0);
  float4 v4 = *(const float4*)(att_v + d0);
  int c = tid & 127, half = tid >> 7;

  float m = -1e30f, lsum = 0.f, acc = 0.f;

  for (int s0 = 0; s0 < S; s0 += 8) {
    __syncthreads();
    for (int lId = tid; lId < 1024; lId += 256) {
      int r = lId >> 7, k = lId & 127;
      st_s[r][k] = stb[(size_t)(s0 + r) * C_ + k];
    }
    __syncthreads();

    float pacc[8][4] = {};
#pragma unroll
    for (int r = 0; r < 8; ++r) {
      const float4* srow4 = (const float4*)(&st_s[r][0]);
#pragma unroll
      for (int q = 0; q < 4; ++q) {
        float4 sv = srow4[kg*4 + q];
        float se[4] = {sv.x, sv.y, sv.z, sv.w};
#pragma unroll
        for (int e = 0; e < 4; ++e)
#pragma unroll
          for (int jj = 0; jj < 4; ++jj)
            pacc[r][jj] += se[e] * wreg[q*4 + e][jj];
      }
    }
#pragma unroll
    for (int r = 0; r < 8; ++r)
      *(float4*)(&pgA[kg][r][jg*4]) =
          make_float4(pacc[r][0], pacc[r][1], pacc[r][2], pacc[r][3]);
    __syncthreads();

    float4 p4 = make_float4(0.f, 0.f, 0.f, 0.f);
#pragma unroll
    for (int k2 = 0; k2 < 8; ++k2) {
      float4 t4 = *(const float4*)(&pgA[k2][kg][d0]);
      p4.x += t4.x; p4.y += t4.y; p4.z += t4.z; p4.w += t4.w;
    }
    float sc = tanhf(p4.x + b4.x) * v4.x + tanhf(p4.y + b4.y) * v4.y +
               tanhf(p4.z + b4.z) * v4.z + tanhf(p4.w + b4.w) * v4.w;
#pragma unroll
    for (int off = 16; off > 0; off >>= 1) sc += __shfl_xor(sc, off, 64);
    if (jg == 0) score_s[kg] = sc;
    __syncthreads();

    float srow[8]; float smax = m;
#pragma unroll
    for (int r = 0; r < 8; ++r) { srow[r] = score_s[r]; smax = fmaxf(smax, srow[r]); }
    float scale = expf(m - smax);
    acc *= scale; lsum *= scale; m = smax;
#pragma unroll
    for (int rr = 0; rr < 4; ++rr) {
      int r = half * 4 + rr;
      float w = expf(srow[r] - m);
      lsum += w;
      acc += w * st_s[r][c];
    }
  }

  __syncthreads();
  if (half == 1) { cm[c] = m; cl[c] = lsum; ca[c] = acc; }
  __syncthreads();
  if (half == 0) {
    float m1 = cm[c], l1 = cl[c], a1 = ca[c];
    float M = fmaxf(m, m1);
    float w0 = expf(m - M), w1 = expf(m1 - M);
    feats[b * 512 + featOff + c] = (acc * w0 + a1 * w1) / (lsum * w0 + l1 * w1);
  }
}

// ---------------------------------------------------------------------------
// Head
// ---------------------------------------------------------------------------
__global__ __launch_bounds__(128) void head_kernel(
    const float* __restrict__ feats, const float* __restrict__ hid_w,
    const float* __restrict__ hid_b, const float* __restrict__ out_w,
    const float* __restrict__ out_b, float* __restrict__ out) {
  __shared__ __align__(16) float f_s[512];
  __shared__ float part[2];
  int b = blockIdx.x, tid = threadIdx.x;
  for (int i = tid; i < 512; i += 128) f_s[i] = feats[b * 512 + i];
  __syncthreads();
  float h = hid_b[tid];
  for (int k = 0; k < 512; ++k) h += f_s[k] * hid_w[k * 128 + tid];
  h = fmaxf(h, 0.f);
  float p = h * out_w[tid];
#pragma unroll
  for (int off = 32; off > 0; off >>= 1) p += __shfl_xor(p, off, 64);
  if ((tid & 63) == 0) part[tid >> 6] = p;
  __syncthreads();
  if (tid == 0) out[b] = part[0] + part[1] + out_b[0];
}

// ---------------------------------------------------------------------------
extern "C" void kernel_launch(void* const* d_in, const int* in_sizes, int n_in,
                              void* d_out, int out_size, void* d_ws, size_t ws_size,
                              hipStream_t stream) {
  const int*   ctx     = (const int*)d_in[0];
  const int*   endseq  = (const int*)d_in[1];
  const int*   ctx_len = (const int*)d_in[2];
  const int*   end_len = (const int*)d_in[3];
  const float* emb     = (const float*)d_in[4];
  const float* fw_gw   = (const float*)d_in[5];
  const float* fw_gb   = (const float*)d_in[6];
  const float* fw_cw   = (const float*)d_in[7];
  const float* fw_cb   = (const float*)d_in[8];
  const float* bw_gw   = (const float*)d_in[9];
  const float* bw_gb   = (const float*)d_in[10];
  const float* bw_cw   = (const float*)d_in[11];
  const float* bw_cb   = (const float*)d_in[12];
  const float* att_v   = (const float*)d_in[13];
  const float* att_w   = (const float*)d_in[14];
  const float* att_b   = (const float*)d_in[15];
  const float* hid_w   = (const float*)d_in[16];
  const float* hid_b   = (const float*)d_in[17];
  const float* out_w   = (const float*)d_in[18];
  const float* out_b   = (const float*)d_in[19];
  float* ws  = (float*)d_ws;
  float* out = (float*)d_out;

  short* Ahi  = (short*)(ws + OFF_ST);
  short* Alo  = Ahi + (size_t)V_ * KP;
  short* Bthi = (short*)(ws + OFF_BT);
  short* Btlo = Bthi + (size_t)NCOL * KP;

  pack_kernel<<<1299, 256, 0, stream>>>(fw_gw, fw_gb, fw_cw, fw_cb,
                                        bw_gw, bw_gb, bw_cw, bw_cb, ws);
  pack_bt<<<(NCOL * KP + 255) / 256, 256, 0, stream>>>(ws + OFF_WXP, Bthi, Btlo);
  pack_emb<<<(int)(((size_t)V_ * KP + 255) / 256), 256, 0, stream>>>(emb, Ahi, Alo);

  dim3 ggrid(6, 391);
  gemm_mfma<<<ggrid, 256, 0, stream>>>(Ahi, Alo, Bthi, Btlo, ws + OFF_PROJ);

  recur_kernel<<<512, 256, 0, stream>>>(ctx, endseq, ctx_len, end_len,
                                        ws + OFF_PROJ, ws + OFF_UALL,
                                        ws + OFF_BIAS, ws + OFF_ST);

  attn_kernel<<<512, 256, 0, stream>>>(ws + OFF_ST, att_v, att_w, att_b,
                                       ws + OFF_FEATS);

  head_kernel<<<128, 128, 0, stream>>>(ws + OFF_FEATS, hid_w, hid_b,
                                       out_w, out_b, out);
}

// Round 9
// 923.763 us; speedup vs baseline: 1.7283x; 1.0702x over previous
//
#include <hip/hip_runtime.h>
#include <cstdint>
#include <cmath>

// Problem constants
static constexpr int V_  = 50000;
static constexpr int E_  = 300;
static constexpr int C_  = 128;
static constexpr int B_  = 128;
static constexpr int SC_ = 512;
static constexpr int SE_ = 64;
static constexpr int NCOL = 768;   // [fw_gate 256 | fw_cand 128 | bw_gate 256 | bw_cand 128]
static constexpr int KP  = 320;    // K padded to 10 x 32 for MFMA

// ws layout (float offsets)
static constexpr size_t OFF_PROJ  = 0;
static constexpr size_t SZ_PROJ   = (size_t)V_ * NCOL;
static constexpr size_t OFF_WXP   = OFF_PROJ + SZ_PROJ;
static constexpr size_t SZ_WXP    = (size_t)304 * NCOL;
static constexpr size_t OFF_UALL  = OFF_WXP + SZ_WXP;
static constexpr size_t SZ_UALL   = (size_t)C_ * NCOL;
static constexpr size_t OFF_BIAS  = OFF_UALL + SZ_UALL;
static constexpr size_t SZ_BIAS   = NCOL;
static constexpr size_t OFF_ST    = OFF_BIAS + SZ_BIAS;
static constexpr size_t SZ_ST_CTX = (size_t)B_ * SC_ * C_;
static constexpr size_t SZ_ST_END = (size_t)B_ * SE_ * C_;
static constexpr size_t SZ_ST     = 2*SZ_ST_CTX + 2*SZ_ST_END;    // 75.5 MB
static constexpr size_t OFF_FEATS = OFF_ST + SZ_ST;
static constexpr size_t SZ_FEATS  = (size_t)B_ * 512;
static constexpr size_t OFF_BT    = OFF_FEATS + SZ_FEATS;
// A_hi/A_lo (bf16) OVERLAP the states region (dead once gemm ends; recur
// zeroes its own tail rows so no global memset is needed).

typedef __attribute__((ext_vector_type(8))) short bf16x8;
typedef __attribute__((ext_vector_type(4))) float f32x4;

static __device__ __forceinline__ unsigned short f2bf_rne(float f) {
  unsigned u = __float_as_uint(f);
  unsigned r = u + 0x7fffu + ((u >> 16) & 1u);
  return (unsigned short)(r >> 16);
}

static __device__ __forceinline__ void gload_lds16(const short* g, short* l) {
  __builtin_amdgcn_global_load_lds(
      (const __attribute__((address_space(1))) void*)g,
      (__attribute__((address_space(3))) void*)l, 16, 0, 0);
}

// LDS-only barrier: s_waitcnt lgkmcnt(0) + s_barrier, WITHOUT the vmcnt(0)
// drain that __syncthreads' workgroup fence forces. Global prefetch loads
// stay in flight across the barrier (backend waits before the actual use).
// simm16 encoding (gfx9/gfx950): vm[3:0]|exp[6:4]|lgkm[11:8]|vm[15:14]
// lgkm=0, vm=63, exp=7 -> 0xC07F.
static __device__ __forceinline__ void lds_barrier() {
  __builtin_amdgcn_s_waitcnt(0xC07F);
  __builtin_amdgcn_s_barrier();
}

// fast activations: __expf + v_rcp_f32 (~1e-6 rel err; logit threshold 7.4e-5)
static __device__ __forceinline__ float fast_sigmoid(float x) {
  return __builtin_amdgcn_rcpf(1.f + __expf(-x));
}
static __device__ __forceinline__ float fast_tanh(float x) {
  return fmaf(-2.f, __builtin_amdgcn_rcpf(__expf(2.f * x) + 1.f), 1.f);
}

// ---------------------------------------------------------------------------
// Pack: Wxp[304][768] fp32, Uall[128][768], bias[768]
// ---------------------------------------------------------------------------
__global__ void pack_kernel(const float* __restrict__ fw_gw, const float* __restrict__ fw_gb,
                            const float* __restrict__ fw_cw, const float* __restrict__ fw_cb,
                            const float* __restrict__ bw_gw, const float* __restrict__ bw_gb,
                            const float* __restrict__ bw_cw, const float* __restrict__ bw_cb,
                            float* __restrict__ ws) {
  int i = blockIdx.x * 256 + threadIdx.x;
  float* Wxp  = ws + OFF_WXP;
  float* Uall = ws + OFF_UALL;
  float* bias = ws + OFF_BIAS;
  if (i < 304 * NCOL) {
    int k = i / NCOL, c = i % NCOL;
    float v = 0.f;
    if (k < 300) {
      if (c < 256)      v = fw_gw[k*256 + c];
      else if (c < 384) v = fw_cw[k*128 + (c-256)];
      else if (c < 640) v = bw_gw[k*256 + (c-384)];
      else              v = bw_cw[k*128 + (c-640)];
    }
    Wxp[i] = v;
    return;
  }
  int j = i - 304 * NCOL;
  if (j >= 0 && j < 128 * NCOL) {
    int k = j / NCOL, c = j % NCOL;
    int kk = 300 + k;
    float v;
    if (c < 256)      v = fw_gw[kk*256 + c];
    else if (c < 384) v = fw_cw[kk*128 + (c-256)];
    else if (c < 640) v = bw_gw[kk*256 + (c-384)];
    else              v = bw_cw[kk*128 + (c-640)];
    Uall[j] = v;
    return;
  }
  int m = j - 128 * NCOL;
  if (m >= 0 && m < NCOL) {
    float v;
    if (m < 256)      v = fw_gb[m];
    else if (m < 384) v = fw_cb[m-256];
    else if (m < 640) v = bw_gb[m-384];
    else              v = bw_cb[m-640];
    bias[m] = v;
  }
}

__global__ void pack_bt(const float* __restrict__ Wxp, short* __restrict__ Bthi,
                        short* __restrict__ Btlo) {
  int i = blockIdx.x * 256 + threadIdx.x;
  if (i >= NCOL * KP) return;
  int k = i % KP, n = i / KP;
  float v = (k < 304) ? Wxp[(size_t)k * NCOL + n] : 0.f;
  unsigned short h = f2bf_rne(v);
  float hf = __uint_as_float((unsigned)h << 16);
  unsigned short lo = f2bf_rne(v - hf);
  Bthi[i] = (short)h;
  Btlo[i] = (short)lo;
}

__global__ void pack_emb(const float* __restrict__ emb, short* __restrict__ Ahi,
                         short* __restrict__ Alo) {
  size_t i = (size_t)blockIdx.x * 256 + threadIdx.x;
  if (i >= (size_t)V_ * KP) return;
  int k = (int)(i % KP);
  size_t row = i / KP;
  float v = (k < E_) ? emb[row * E_ + k] : 0.f;
  unsigned short h = f2bf_rne(v);
  float hf = __uint_as_float((unsigned)h << 16);
  unsigned short lo = f2bf_rne(v - hf);
  Ahi[i] = (short)h;
  Alo[i] = (short)lo;
}

// ---------------------------------------------------------------------------
// proj = emb @ Wxp via bf16x3 split MFMA (m97 structure)
// ---------------------------------------------------------------------------
__global__ __launch_bounds__(256) void gemm_mfma(
    const short* __restrict__ Ahi, const short* __restrict__ Alo,
    const short* __restrict__ Bthi, const short* __restrict__ Btlo,
    float* __restrict__ proj) {
  __shared__ short lds[16384];
  int tid = threadIdx.x, wid = tid >> 6, lane = tid & 63;
  int n0 = blockIdx.x * 128, m0 = blockIdx.y * 128;
  f32x4 acc[4][4] = {};

  int lr = lane >> 2, lc = lane & 3;
  int q0 = wid * 2, q1 = q0 + 1;
  int r0 = q0 * 16 + lr, r1 = q1 * 16 + lr;
  int am0 = m0 + r0; if (am0 > V_ - 1) am0 = V_ - 1;
  int am1 = m0 + r1; if (am1 > V_ - 1) am1 = V_ - 1;
  size_t gaOff0 = (size_t)am0 * KP + lc * 8;
  size_t gaOff1 = (size_t)am1 * KP + lc * 8;
  size_t gbOff0 = (size_t)(n0 + r0) * KP + lc * 8;
  size_t gbOff1 = (size_t)(n0 + r1) * KP + lc * 8;

  int quad = lane >> 4;
  int arow = (wid >> 1) * 64 + (lane & 15);
  int brow = (wid & 1) * 64 + (lane & 15);

  for (int k0 = 0; k0 < KP; k0 += 32) {
    gload_lds16(Ahi  + gaOff0 + k0, lds +         q0 * 512);
    gload_lds16(Ahi  + gaOff1 + k0, lds +         q1 * 512);
    gload_lds16(Alo  + gaOff0 + k0, lds +  4096 + q0 * 512);
    gload_lds16(Alo  + gaOff1 + k0, lds +  4096 + q1 * 512);
    gload_lds16(Bthi + gbOff0 + k0, lds +  8192 + q0 * 512);
    gload_lds16(Bthi + gbOff1 + k0, lds +  8192 + q1 * 512);
    gload_lds16(Btlo + gbOff0 + k0, lds + 12288 + q0 * 512);
    gload_lds16(Btlo + gbOff1 + k0, lds + 12288 + q1 * 512);
    __syncthreads();

    bf16x8 ah[4], al[4], bh[4], bl[4];
#pragma unroll
    for (int i = 0; i < 4; ++i) {
      ah[i] = *(bf16x8*)&lds[        (arow + i*16) * 32 + quad * 8];
      al[i] = *(bf16x8*)&lds[ 4096 + (arow + i*16) * 32 + quad * 8];
      bh[i] = *(bf16x8*)&lds[ 8192 + (brow + i*16) * 32 + quad * 8];
      bl[i] = *(bf16x8*)&lds[12288 + (brow + i*16) * 32 + quad * 8];
    }
#pragma unroll
    for (int i = 0; i < 4; ++i)
#pragma unroll
      for (int j = 0; j < 4; ++j) {
        acc[i][j] = __builtin_amdgcn_mfma_f32_16x16x32_bf16(ah[i], bh[j], acc[i][j], 0, 0, 0);
        acc[i][j] = __builtin_amdgcn_mfma_f32_16x16x32_bf16(ah[i], bl[j], acc[i][j], 0, 0, 0);
        acc[i][j] = __builtin_amdgcn_mfma_f32_16x16x32_bf16(al[i], bh[j], acc[i][j], 0, 0, 0);
      }
    __syncthreads();
  }

  int colb = n0 + (wid & 1) * 64 + (lane & 15);
  int rowb = m0 + (wid >> 1) * 64 + quad * 4;
#pragma unroll
  for (int i = 0; i < 4; ++i) {
    int rb = rowb + i * 16;
#pragma unroll
    for (int j = 0; j < 4; ++j) {
      int cc = colb + j * 16;
#pragma unroll
      for (int r = 0; r < 4; ++r) {
        int rr = rb + r;
        if (rr < V_) proj[(size_t)rr * NCOL + cc] = acc[i][j][r];
      }
    }
  }
}

// ---------------------------------------------------------------------------
// Recurrence v10: round-5's best-measured dataflow (k-sliced partials, 4
// barriers/step, weights resident at waves_per_eu(2,2)) with __syncthreads
// replaced by lds_barrier() — s_waitcnt lgkmcnt(0) + s_barrier, NO vmcnt
// drain. The per-step global prefetch loads (next token's x-projection) and
// the h state store stay in flight across barriers instead of being forced
// to complete inside the serial critical path at every barrier.
// ---------------------------------------------------------------------------
__global__ __attribute__((amdgpu_flat_work_group_size(256, 256),
                          amdgpu_waves_per_eu(2, 2)))
void recur_kernel(
    const int* __restrict__ ctx, const int* __restrict__ endseq,
    const int* __restrict__ ctx_len, const int* __restrict__ end_len,
    const float* __restrict__ proj, const float* __restrict__ Uall,
    const float* __restrict__ bias, float* __restrict__ states) {
  __shared__ __align__(16) float h_s[128];
  __shared__ __align__(16) float rh_s[128];
  __shared__ __align__(16) float u_s[128];
  __shared__ __align__(16) float pg[8][260];
  __shared__ __align__(16) float pc[8][132];

  int bid = blockIdx.x;
  int tid = threadIdx.x;
  const int* seq; int S, L, b, dir; float* stbase;
  if (bid < 256) {
    b = bid >> 1; dir = bid & 1;
    seq = ctx + b * SC_; S = SC_; L = ctx_len[b];
    stbase = states + (dir ? SZ_ST_CTX : 0) + (size_t)b * SC_ * C_;
  } else {
    int q = bid - 256; b = q >> 1; dir = q & 1;
    seq = endseq + b * SE_; S = SE_; L = end_len[b];
    stbase = states + 2*SZ_ST_CTX + (dir ? SZ_ST_END : 0) + (size_t)b * SE_ * C_;
  }
  int dirOff = dir ? 384 : 0;
  int kg = tid >> 5, jg = tid & 31;

  // gate block 16k x 8j (128 VGPRs) + cand block 16k x 4j (64 VGPRs)
  float wg[16][8];
  float wc[16][4];
#pragma unroll
  for (int kk = 0; kk < 16; ++kk) {
    const float* up = Uall + (size_t)(kg*16 + kk) * NCOL + dirOff;
    float4 w0 = *(const float4*)(up + jg*8);
    float4 w1 = *(const float4*)(up + jg*8 + 4);
    wg[kk][0]=w0.x; wg[kk][1]=w0.y; wg[kk][2]=w0.z; wg[kk][3]=w0.w;
    wg[kk][4]=w1.x; wg[kk][5]=w1.y; wg[kk][6]=w1.z; wg[kk][7]=w1.w;
    float4 wv = *(const float4*)(up + 256 + jg*4);
    wc[kk][0]=wv.x; wc[kk][1]=wv.y; wc[kk][2]=wv.z; wc[kk][3]=wv.w;
  }
  float bias_g = bias[dirOff + tid];
  float bias_c = (tid < 128) ? bias[dirOff + 256 + tid] : 0.f;

  if (tid < 128) h_s[tid] = 0.f;
  lds_barrier();

  // prefetch step 0's x-projection
  int pos0 = dir ? (L - 1) : 0;
  int tok0 = seq[pos0];
  const float* xr0 = proj + (size_t)tok0 * NCOL + dirOff;
  float xg = xr0[tid];
  float xc = (tid < 128) ? xr0[256 + tid] : 0.f;

  for (int t = 0; t < L; ++t) {
    // prefetch next step (stays in flight across barriers — no vmcnt drain)
    float xg_n = 0.f, xc_n = 0.f;
    if (t + 1 < L) {
      int pos_n = dir ? (L - 2 - t) : (t + 1);
      int tok_n = seq[pos_n];
      const float* xr = proj + (size_t)tok_n * NCOL + dirOff;
      xg_n = xr[tid];
      xc_n = (tid < 128) ? xr[256 + tid] : 0.f;
    }

    // phase 1: gate partials (h broadcast reads; 8 acc chains for ILP)
    float a[8] = {0.f,0.f,0.f,0.f,0.f,0.f,0.f,0.f};
    const float4* h4 = (const float4*)h_s;
#pragma unroll
    for (int q = 0; q < 4; ++q) {
      float4 hv = h4[kg*4 + q];
      float he[4] = {hv.x, hv.y, hv.z, hv.w};
#pragma unroll
      for (int e = 0; e < 4; ++e)
#pragma unroll
        for (int jj = 0; jj < 8; ++jj)
          a[jj] += he[e] * wg[q*4 + e][jj];
    }
    *(float4*)(&pg[kg][jg*8])     = make_float4(a[0], a[1], a[2], a[3]);
    *(float4*)(&pg[kg][jg*8 + 4]) = make_float4(a[4], a[5], a[6], a[7]);
    lds_barrier();   // B1

    // gate consume: column tid
    float g = xg + bias_g;
#pragma unroll
    for (int k2 = 0; k2 < 8; ++k2) g += pg[k2][tid];
    g = fast_sigmoid(g);

    float h_old = 0.f;
    if (tid < 128) { h_old = h_s[tid]; rh_s[tid] = g * h_old; }
    else           { u_s[tid - 128] = g; }
    lds_barrier();   // B2

    // phase 2: cand partials
    float ac[4] = {0.f, 0.f, 0.f, 0.f};
    const float4* rh4 = (const float4*)rh_s;
#pragma unroll
    for (int q = 0; q < 4; ++q) {
      float4 rv = rh4[kg*4 + q];
      float re[4] = {rv.x, rv.y, rv.z, rv.w};
#pragma unroll
      for (int e = 0; e < 4; ++e)
#pragma unroll
        for (int jj = 0; jj < 4; ++jj)
          ac[jj] += re[e] * wc[q*4 + e][jj];
    }
    *(float4*)(&pc[kg][jg*4]) = make_float4(ac[0], ac[1], ac[2], ac[3]);
    lds_barrier();   // B3

    // cand consume + h update
    if (tid < 128) {
      float cs = xc + bias_c;
#pragma unroll
      for (int k2 = 0; k2 < 8; ++k2) cs += pc[k2][tid];
      float c = fast_tanh(cs);
      float u = u_s[tid];
      float hn = u * h_old + (1.f - u) * c;
      h_s[tid] = hn;
      int pos = dir ? (L - 1 - t) : t;
      stbase[(size_t)pos * C_ + tid] = hn;
    }
    lds_barrier();   // B4
    xg = xg_n; xc = xc_n;
  }

  // zero tail rows [L, S) — replaces the global memset of states
  for (int i = L * C_ + tid; i < S * C_; i += 256) stbase[i] = 0.f;
}

// ---------------------------------------------------------------------------
// Attention: one WG per (b, array); flash-style online softmax.
// ---------------------------------------------------------------------------
__global__ __launch_bounds__(256, 2) void attn_kernel(
    const float* __restrict__ states, const float* __restrict__ att_v,
    const float* __restrict__ att_w, const float* __restrict__ att_b,
    float* __restrict__ feats) {
  __shared__ __align__(16) float st_s[8][132];
  __shared__ __align__(16) float pgA[8][8][132];
  __shared__ float score_s[8];
  __shared__ float cm[128], cl[128], ca[128];

  int bid = blockIdx.x, tid = threadIdx.x;
  int b, dir, S, featOff; const float* stb;
  if (bid < 256) {
    b = bid >> 1; dir = bid & 1; S = SC_;
    stb = states + (dir ? SZ_ST_CTX : 0) + (size_t)b * SC_ * C_;
    featOff = dir * 128;
  } else {
    int q = bid - 256; b = q >> 1; dir = q & 1; S = SE_;
    stb = states + 2*SZ_ST_CTX + (dir ? SZ_ST_END : 0) + (size_t)b * SE_ * C_;
    featOff = 256 + dir * 128;
  }

  int kg = tid >> 5, jg = tid & 31;
  float wreg[16][4];
#pragma unroll
  for (int kk = 0; kk < 16; ++kk) {
    float4 wv = *(const float4*)(att_w + (size_t)(kg*16 + kk) * C_ + jg*4);
    wreg[kk][0]=wv.x; wreg[kk][1]=wv.y; wreg[kk][2]=wv.z; wreg[kk][3]=wv.w;
  }
  int d0 = jg * 4;
  float4 b4 = *(const float4*)(att_b + d0);
  float4 v4 = *(const float4*)(att_v + d0);
  int c = tid & 127, half = tid >> 7;

  float m = -1e30f, lsum = 0.f, acc = 0.f;

  for (int s0 = 0; s0 < S; s0 += 8) {
    __syncthreads();
    for (int lId = tid; lId < 1024; lId += 256) {
      int r = lId >> 7, k = lId & 127;
      st_s[r][k] = stb[(size_t)(s0 + r) * C_ + k];
    }
    __syncthreads();

    float pacc[8][4] = {};
#pragma unroll
    for (int r = 0; r < 8; ++r) {
      const float4* srow4 = (const float4*)(&st_s[r][0]);
#pragma unroll
      for (int q = 0; q < 4; ++q) {
        float4 sv = srow4[kg*4 + q];
        float se[4] = {sv.x, sv.y, sv.z, sv.w};
#pragma unroll
        for (int e = 0; e < 4; ++e)
#pragma unroll
          for (int jj = 0; jj < 4; ++jj)
            pacc[r][jj] += se[e] * wreg[q*4 + e][jj];
      }
    }
#pragma unroll
    for (int r = 0; r < 8; ++r)
      *(float4*)(&pgA[kg][r][jg*4]) =
          make_float4(pacc[r][0], pacc[r][1], pacc[r][2], pacc[r][3]);
    __syncthreads();

    float4 p4 = make_float4(0.f, 0.f, 0.f, 0.f);
#pragma unroll
    for (int k2 = 0; k2 < 8; ++k2) {
      float4 t4 = *(const float4*)(&pgA[k2][kg][d0]);
      p4.x += t4.x; p4.y += t4.y; p4.z += t4.z; p4.w += t4.w;
    }
    float sc = tanhf(p4.x + b4.x) * v4.x + tanhf(p4.y + b4.y) * v4.y +
               tanhf(p4.z + b4.z) * v4.z + tanhf(p4.w + b4.w) * v4.w;
#pragma unroll
    for (int off = 16; off > 0; off >>= 1) sc += __shfl_xor(sc, off, 64);
    if (jg == 0) score_s[kg] = sc;
    __syncthreads();

    float srow[8]; float smax = m;
#pragma unroll
    for (int r = 0; r < 8; ++r) { srow[r] = score_s[r]; smax = fmaxf(smax, srow[r]); }
    float scale = expf(m - smax);
    acc *= scale; lsum *= scale; m = smax;
#pragma unroll
    for (int rr = 0; rr < 4; ++rr) {
      int r = half * 4 + rr;
      float w = expf(srow[r] - m);
      lsum += w;
      acc += w * st_s[r][c];
    }
  }

  __syncthreads();
  if (half == 1) { cm[c] = m; cl[c] = lsum; ca[c] = acc; }
  __syncthreads();
  if (half == 0) {
    float m1 = cm[c], l1 = cl[c], a1 = ca[c];
    float M = fmaxf(m, m1);
    float w0 = expf(m - M), w1 = expf(m1 - M);
    feats[b * 512 + featOff + c] = (acc * w0 + a1 * w1) / (lsum * w0 + l1 * w1);
  }
}

// ---------------------------------------------------------------------------
// Head
// ---------------------------------------------------------------------------
__global__ __launch_bounds__(128) void head_kernel(
    const float* __restrict__ feats, const float* __restrict__ hid_w,
    const float* __restrict__ hid_b, const float* __restrict__ out_w,
    const float* __restrict__ out_b, float* __restrict__ out) {
  __shared__ __align__(16) float f_s[512];
  __shared__ float part[2];
  int b = blockIdx.x, tid = threadIdx.x;
  for (int i = tid; i < 512; i += 128) f_s[i] = feats[b * 512 + i];
  __syncthreads();
  float h = hid_b[tid];
  for (int k = 0; k < 512; ++k) h += f_s[k] * hid_w[k * 128 + tid];
  h = fmaxf(h, 0.f);
  float p = h * out_w[tid];
#pragma unroll
  for (int off = 32; off > 0; off >>= 1) p += __shfl_xor(p, off, 64);
  if ((tid & 63) == 0) part[tid >> 6] = p;
  __syncthreads();
  if (tid == 0) out[b] = part[0] + part[1] + out_b[0];
}

// ---------------------------------------------------------------------------
extern "C" void kernel_launch(void* const* d_in, const int* in_sizes, int n_in,
                              void* d_out, int out_size, void* d_ws, size_t ws_size,
                              hipStream_t stream) {
  const int*   ctx     = (const int*)d_in[0];
  const int*   endseq  = (const int*)d_in[1];
  const int*   ctx_len = (const int*)d_in[2];
  const int*   end_len = (const int*)d_in[3];
  const float* emb     = (const float*)d_in[4];
  const float* fw_gw   = (const float*)d_in[5];
  const float* fw_gb   = (const float*)d_in[6];
  const float* fw_cw   = (const float*)d_in[7];
  const float* fw_cb   = (const float*)d_in[8];
  const float* bw_gw   = (const float*)d_in[9];
  const float* bw_gb   = (const float*)d_in[10];
  const float* bw_cw   = (const float*)d_in[11];
  const float* bw_cb   = (const float*)d_in[12];
  const float* att_v   = (const float*)d_in[13];
  const float* att_w   = (const float*)d_in[14];
  const float* att_b   = (const float*)d_in[15];
  const float* hid_w   = (const float*)d_in[16];
  const float* hid_b   = (const float*)d_in[17];
  const float* out_w   = (const float*)d_in[18];
  const float* out_b   = (const float*)d_in[19];
  float* ws  = (float*)d_ws;
  float* out = (float*)d_out;

  short* Ahi  = (short*)(ws + OFF_ST);
  short* Alo  = Ahi + (size_t)V_ * KP;
  short* Bthi = (short*)(ws + OFF_BT);
  short* Btlo = Bthi + (size_t)NCOL * KP;

  pack_kernel<<<1299, 256, 0, stream>>>(fw_gw, fw_gb, fw_cw, fw_cb,
                                        bw_gw, bw_gb, bw_cw, bw_cb, ws);
  pack_bt<<<(NCOL * KP + 255) / 256, 256, 0, stream>>>(ws + OFF_WXP, Bthi, Btlo);
  pack_emb<<<(int)(((size_t)V_ * KP + 255) / 256), 256, 0, stream>>>(emb, Ahi, Alo);

  dim3 ggrid(6, 391);
  gemm_mfma<<<ggrid, 256, 0, stream>>>(Ahi, Alo, Bthi, Btlo, ws + OFF_PROJ);

  recur_kernel<<<512, 256, 0, stream>>>(ctx, endseq, ctx_len, end_len,
                                        ws + OFF_PROJ, ws + OFF_UALL,
                                        ws + OFF_BIAS, ws + OFF_ST);

  attn_kernel<<<512, 256, 0, stream>>>(ws + OFF_ST, att_v, att_w, att_b,
                                       ws + OFF_FEATS);

  head_kernel<<<128, 128, 0, stream>>>(ws + OFF_FEATS, hid_w, hid_b,
                                       out_w, out_b, out);
}

// Round 10
// 764.369 us; speedup vs baseline: 2.0887x; 1.2085x over previous
//
#include <hip/hip_runtime.h>
#include <cstdint>
#include <cmath>

// Problem constants
static constexpr int V_  = 50000;
static constexpr int E_  = 300;
static constexpr int C_  = 128;
static constexpr int B_  = 128;
static constexpr int SC_ = 512;
static constexpr int SE_ = 64;
static constexpr int NCOL = 768;   // [fw_gate 256 | fw_cand 128 | bw_gate 256 | bw_cand 128]
static constexpr int KP  = 320;    // K padded to 10 x 32 for MFMA

// ws layout (float offsets)
static constexpr size_t OFF_PROJ  = 0;
static constexpr size_t SZ_PROJ   = (size_t)V_ * NCOL;
static constexpr size_t OFF_WXP   = OFF_PROJ + SZ_PROJ;
static constexpr size_t SZ_WXP    = (size_t)304 * NCOL;
static constexpr size_t OFF_UALL  = OFF_WXP + SZ_WXP;
static constexpr size_t SZ_UALL   = (size_t)C_ * NCOL;
static constexpr size_t OFF_BIAS  = OFF_UALL + SZ_UALL;
static constexpr size_t SZ_BIAS   = NCOL;
static constexpr size_t OFF_ST    = OFF_BIAS + SZ_BIAS;
static constexpr size_t SZ_ST_CTX = (size_t)B_ * SC_ * C_;
static constexpr size_t SZ_ST_END = (size_t)B_ * SE_ * C_;
static constexpr size_t SZ_ST     = 2*SZ_ST_CTX + 2*SZ_ST_END;    // 75.5 MB
static constexpr size_t OFF_FEATS = OFF_ST + SZ_ST;
static constexpr size_t SZ_FEATS  = (size_t)B_ * 512;
static constexpr size_t OFF_BT    = OFF_FEATS + SZ_FEATS;
static constexpr size_t SZ_BT     = (size_t)NCOL * KP / 2 * 2;    // 2 short arrays
static constexpr size_t OFF_AWT   = OFF_BT + SZ_BT;               // att_w^T hi/lo shorts
// A_hi/A_lo (bf16) OVERLAP the states region (dead once gemm ends; recur
// zeroes its own tail rows so no global memset is needed).

typedef __attribute__((ext_vector_type(8))) short bf16x8;
typedef __attribute__((ext_vector_type(4))) float f32x4;

static __device__ __forceinline__ unsigned short f2bf_rne(float f) {
  unsigned u = __float_as_uint(f);
  unsigned r = u + 0x7fffu + ((u >> 16) & 1u);
  return (unsigned short)(r >> 16);
}

static __device__ __forceinline__ void gload_lds16(const short* g, short* l) {
  __builtin_amdgcn_global_load_lds(
      (const __attribute__((address_space(1))) void*)g,
      (__attribute__((address_space(3))) void*)l, 16, 0, 0);
}

// fast activations: __expf + v_rcp_f32 (~1e-6 rel err; logit threshold 7.4e-5)
static __device__ __forceinline__ float fast_sigmoid(float x) {
  return __builtin_amdgcn_rcpf(1.f + __expf(-x));
}
static __device__ __forceinline__ float fast_tanh(float x) {
  return fmaf(-2.f, __builtin_amdgcn_rcpf(__expf(2.f * x) + 1.f), 1.f);
}

// ---------------------------------------------------------------------------
// Pack: Wxp[304][768] fp32, Uall[128][768], bias[768]
// ---------------------------------------------------------------------------
__global__ void pack_kernel(const float* __restrict__ fw_gw, const float* __restrict__ fw_gb,
                            const float* __restrict__ fw_cw, const float* __restrict__ fw_cb,
                            const float* __restrict__ bw_gw, const float* __restrict__ bw_gb,
                            const float* __restrict__ bw_cw, const float* __restrict__ bw_cb,
                            float* __restrict__ ws) {
  int i = blockIdx.x * 256 + threadIdx.x;
  float* Wxp  = ws + OFF_WXP;
  float* Uall = ws + OFF_UALL;
  float* bias = ws + OFF_BIAS;
  if (i < 304 * NCOL) {
    int k = i / NCOL, c = i % NCOL;
    float v = 0.f;
    if (k < 300) {
      if (c < 256)      v = fw_gw[k*256 + c];
      else if (c < 384) v = fw_cw[k*128 + (c-256)];
      else if (c < 640) v = bw_gw[k*256 + (c-384)];
      else              v = bw_cw[k*128 + (c-640)];
    }
    Wxp[i] = v;
    return;
  }
  int j = i - 304 * NCOL;
  if (j >= 0 && j < 128 * NCOL) {
    int k = j / NCOL, c = j % NCOL;
    int kk = 300 + k;
    float v;
    if (c < 256)      v = fw_gw[kk*256 + c];
    else if (c < 384) v = fw_cw[kk*128 + (c-256)];
    else if (c < 640) v = bw_gw[kk*256 + (c-384)];
    else              v = bw_cw[kk*128 + (c-640)];
    Uall[j] = v;
    return;
  }
  int m = j - 128 * NCOL;
  if (m >= 0 && m < NCOL) {
    float v;
    if (m < 256)      v = fw_gb[m];
    else if (m < 384) v = fw_cb[m-256];
    else if (m < 640) v = bw_gb[m-384];
    else              v = bw_cb[m-640];
    bias[m] = v;
  }
}

// Bt hi/lo for the proj GEMM + att_w^T hi/lo for the MFMA attention
__global__ void pack_bt(const float* __restrict__ Wxp, short* __restrict__ Bthi,
                        short* __restrict__ Btlo, const float* __restrict__ att_w,
                        short* __restrict__ awt_hi, short* __restrict__ awt_lo) {
  int i = blockIdx.x * 256 + threadIdx.x;
  if (i < NCOL * KP) {
    int k = i % KP, n = i / KP;
    float v = (k < 304) ? Wxp[(size_t)k * NCOL + n] : 0.f;
    unsigned short h = f2bf_rne(v);
    float hf = __uint_as_float((unsigned)h << 16);
    unsigned short lo = f2bf_rne(v - hf);
    Bthi[i] = (short)h;
    Btlo[i] = (short)lo;
    return;
  }
  int j = i - NCOL * KP;
  if (j < 128 * 128) {
    int d = j >> 7, c = j & 127;
    float v = att_w[(size_t)c * 128 + d];   // transpose: awt[d][k=c]
    unsigned short h = f2bf_rne(v);
    float hf = __uint_as_float((unsigned)h << 16);
    unsigned short lo = f2bf_rne(v - hf);
    awt_hi[j] = (short)h;
    awt_lo[j] = (short)lo;
  }
}

__global__ void pack_emb(const float* __restrict__ emb, short* __restrict__ Ahi,
                         short* __restrict__ Alo) {
  size_t i = (size_t)blockIdx.x * 256 + threadIdx.x;
  if (i >= (size_t)V_ * KP) return;
  int k = (int)(i % KP);
  size_t row = i / KP;
  float v = (k < E_) ? emb[row * E_ + k] : 0.f;
  unsigned short h = f2bf_rne(v);
  float hf = __uint_as_float((unsigned)h << 16);
  unsigned short lo = f2bf_rne(v - hf);
  Ahi[i] = (short)h;
  Alo[i] = (short)lo;
}

// ---------------------------------------------------------------------------
// proj = emb @ Wxp via bf16x3 split MFMA (m97 structure)
// ---------------------------------------------------------------------------
__global__ __launch_bounds__(256) void gemm_mfma(
    const short* __restrict__ Ahi, const short* __restrict__ Alo,
    const short* __restrict__ Bthi, const short* __restrict__ Btlo,
    float* __restrict__ proj) {
  __shared__ short lds[16384];
  int tid = threadIdx.x, wid = tid >> 6, lane = tid & 63;
  int n0 = blockIdx.x * 128, m0 = blockIdx.y * 128;
  f32x4 acc[4][4] = {};

  int lr = lane >> 2, lc = lane & 3;
  int q0 = wid * 2, q1 = q0 + 1;
  int r0 = q0 * 16 + lr, r1 = q1 * 16 + lr;
  int am0 = m0 + r0; if (am0 > V_ - 1) am0 = V_ - 1;
  int am1 = m0 + r1; if (am1 > V_ - 1) am1 = V_ - 1;
  size_t gaOff0 = (size_t)am0 * KP + lc * 8;
  size_t gaOff1 = (size_t)am1 * KP + lc * 8;
  size_t gbOff0 = (size_t)(n0 + r0) * KP + lc * 8;
  size_t gbOff1 = (size_t)(n0 + r1) * KP + lc * 8;

  int quad = lane >> 4;
  int arow = (wid >> 1) * 64 + (lane & 15);
  int brow = (wid & 1) * 64 + (lane & 15);

  for (int k0 = 0; k0 < KP; k0 += 32) {
    gload_lds16(Ahi  + gaOff0 + k0, lds +         q0 * 512);
    gload_lds16(Ahi  + gaOff1 + k0, lds +         q1 * 512);
    gload_lds16(Alo  + gaOff0 + k0, lds +  4096 + q0 * 512);
    gload_lds16(Alo  + gaOff1 + k0, lds +  4096 + q1 * 512);
    gload_lds16(Bthi + gbOff0 + k0, lds +  8192 + q0 * 512);
    gload_lds16(Bthi + gbOff1 + k0, lds +  8192 + q1 * 512);
    gload_lds16(Btlo + gbOff0 + k0, lds + 12288 + q0 * 512);
    gload_lds16(Btlo + gbOff1 + k0, lds + 12288 + q1 * 512);
    __syncthreads();

    bf16x8 ah[4], al[4], bh[4], bl[4];
#pragma unroll
    for (int i = 0; i < 4; ++i) {
      ah[i] = *(bf16x8*)&lds[        (arow + i*16) * 32 + quad * 8];
      al[i] = *(bf16x8*)&lds[ 4096 + (arow + i*16) * 32 + quad * 8];
      bh[i] = *(bf16x8*)&lds[ 8192 + (brow + i*16) * 32 + quad * 8];
      bl[i] = *(bf16x8*)&lds[12288 + (brow + i*16) * 32 + quad * 8];
    }
#pragma unroll
    for (int i = 0; i < 4; ++i)
#pragma unroll
      for (int j = 0; j < 4; ++j) {
        acc[i][j] = __builtin_amdgcn_mfma_f32_16x16x32_bf16(ah[i], bh[j], acc[i][j], 0, 0, 0);
        acc[i][j] = __builtin_amdgcn_mfma_f32_16x16x32_bf16(ah[i], bl[j], acc[i][j], 0, 0, 0);
        acc[i][j] = __builtin_amdgcn_mfma_f32_16x16x32_bf16(al[i], bh[j], acc[i][j], 0, 0, 0);
      }
    __syncthreads();
  }

  int colb = n0 + (wid & 1) * 64 + (lane & 15);
  int rowb = m0 + (wid >> 1) * 64 + quad * 4;
#pragma unroll
  for (int i = 0; i < 4; ++i) {
    int rb = rowb + i * 16;
#pragma unroll
    for (int j = 0; j < 4; ++j) {
      int cc = colb + j * 16;
#pragma unroll
      for (int r = 0; r < 4; ++r) {
        int rr = rb + r;
        if (rr < V_) proj[(size_t)rr * NCOL + cc] = acc[i][j][r];
      }
    }
  }
}

// ---------------------------------------------------------------------------
// Recurrence (round-5 best-measured, 469 us): k-sliced partials, 4 barriers,
// weights resident at waves_per_eu(2,2). Six dataflow variants (r5-r10) all
// land 470-550 us — this is the structural plateau for chain-per-WG.
// ---------------------------------------------------------------------------
__global__ __attribute__((amdgpu_flat_work_group_size(256, 256),
                          amdgpu_waves_per_eu(2, 2)))
void recur_kernel(
    const int* __restrict__ ctx, const int* __restrict__ endseq,
    const int* __restrict__ ctx_len, const int* __restrict__ end_len,
    const float* __restrict__ proj, const float* __restrict__ Uall,
    const float* __restrict__ bias, float* __restrict__ states) {
  __shared__ __align__(16) float h_s[128];
  __shared__ __align__(16) float rh_s[128];
  __shared__ __align__(16) float u_s[128];
  __shared__ __align__(16) float pg[8][260];
  __shared__ __align__(16) float pc[8][132];

  int bid = blockIdx.x;
  int tid = threadIdx.x;
  const int* seq; int S, L, b, dir; float* stbase;
  if (bid < 256) {
    b = bid >> 1; dir = bid & 1;
    seq = ctx + b * SC_; S = SC_; L = ctx_len[b];
    stbase = states + (dir ? SZ_ST_CTX : 0) + (size_t)b * SC_ * C_;
  } else {
    int q = bid - 256; b = q >> 1; dir = q & 1;
    seq = endseq + b * SE_; S = SE_; L = end_len[b];
    stbase = states + 2*SZ_ST_CTX + (dir ? SZ_ST_END : 0) + (size_t)b * SE_ * C_;
  }
  int dirOff = dir ? 384 : 0;
  int kg = tid >> 5, jg = tid & 31;

  float wg[16][8];
  float wc[16][4];
#pragma unroll
  for (int kk = 0; kk < 16; ++kk) {
    const float* up = Uall + (size_t)(kg*16 + kk) * NCOL + dirOff;
    float4 w0 = *(const float4*)(up + jg*8);
    float4 w1 = *(const float4*)(up + jg*8 + 4);
    wg[kk][0]=w0.x; wg[kk][1]=w0.y; wg[kk][2]=w0.z; wg[kk][3]=w0.w;
    wg[kk][4]=w1.x; wg[kk][5]=w1.y; wg[kk][6]=w1.z; wg[kk][7]=w1.w;
    float4 wv = *(const float4*)(up + 256 + jg*4);
    wc[kk][0]=wv.x; wc[kk][1]=wv.y; wc[kk][2]=wv.z; wc[kk][3]=wv.w;
  }
  float bias_g = bias[dirOff + tid];
  float bias_c = (tid < 128) ? bias[dirOff + 256 + tid] : 0.f;

  if (tid < 128) h_s[tid] = 0.f;
  __syncthreads();

  int pos0 = dir ? (L - 1) : 0;
  int tok0 = seq[pos0];
  const float* xr0 = proj + (size_t)tok0 * NCOL + dirOff;
  float xg = xr0[tid];
  float xc = (tid < 128) ? xr0[256 + tid] : 0.f;

  for (int t = 0; t < L; ++t) {
    float xg_n = 0.f, xc_n = 0.f;
    if (t + 1 < L) {
      int pos_n = dir ? (L - 2 - t) : (t + 1);
      int tok_n = seq[pos_n];
      const float* xr = proj + (size_t)tok_n * NCOL + dirOff;
      xg_n = xr[tid];
      xc_n = (tid < 128) ? xr[256 + tid] : 0.f;
    }

    float a[8] = {0.f,0.f,0.f,0.f,0.f,0.f,0.f,0.f};
    const float4* h4 = (const float4*)h_s;
#pragma unroll
    for (int q = 0; q < 4; ++q) {
      float4 hv = h4[kg*4 + q];
      float he[4] = {hv.x, hv.y, hv.z, hv.w};
#pragma unroll
      for (int e = 0; e < 4; ++e)
#pragma unroll
        for (int jj = 0; jj < 8; ++jj)
          a[jj] += he[e] * wg[q*4 + e][jj];
    }
    *(float4*)(&pg[kg][jg*8])     = make_float4(a[0], a[1], a[2], a[3]);
    *(float4*)(&pg[kg][jg*8 + 4]) = make_float4(a[4], a[5], a[6], a[7]);
    __syncthreads();   // B1

    float g = xg + bias_g;
#pragma unroll
    for (int k2 = 0; k2 < 8; ++k2) g += pg[k2][tid];
    g = fast_sigmoid(g);

    float h_old = 0.f;
    if (tid < 128) { h_old = h_s[tid]; rh_s[tid] = g * h_old; }
    else           { u_s[tid - 128] = g; }
    __syncthreads();   // B2

    float ac[4] = {0.f, 0.f, 0.f, 0.f};
    const float4* rh4 = (const float4*)rh_s;
#pragma unroll
    for (int q = 0; q < 4; ++q) {
      float4 rv = rh4[kg*4 + q];
      float re[4] = {rv.x, rv.y, rv.z, rv.w};
#pragma unroll
      for (int e = 0; e < 4; ++e)
#pragma unroll
        for (int jj = 0; jj < 4; ++jj)
          ac[jj] += re[e] * wc[q*4 + e][jj];
    }
    *(float4*)(&pc[kg][jg*4]) = make_float4(ac[0], ac[1], ac[2], ac[3]);
    __syncthreads();   // B3

    if (tid < 128) {
      float cs = xc + bias_c;
#pragma unroll
      for (int k2 = 0; k2 < 8; ++k2) cs += pc[k2][tid];
      float c = fast_tanh(cs);
      float u = u_s[tid];
      float hn = u * h_old + (1.f - u) * c;
      h_s[tid] = hn;
      int pos = dir ? (L - 1 - t) : t;
      stbase[(size_t)pos * C_ + tid] = hn;
    }
    __syncthreads();   // B4
    xg = xg_n; xc = xc_n;
  }

  for (int i = L * C_ + tid; i < S * C_; i += 256) stbase[i] = 0.f;
}

// ---------------------------------------------------------------------------
// Attention v2: MFMA bf16x3 score projection. Per WG (b, dir, arr):
// B-frags = att_w^T hi/lo in registers (wave w owns d-cols [32w,+32)).
// Chunks of 16 state rows: stage fp32 + bf16 hi/lo to LDS (1-chunk register
// prefetch), 24 mfma/wave, epilogue tanh*v + quad-shfl + spart reduce,
// online softmax (half = rows 0-7 / 8-15; halves merged at end).
// ---------------------------------------------------------------------------
__global__ __launch_bounds__(256, 2) void attn_kernel(
    const float* __restrict__ states, const short* __restrict__ awt_hi,
    const short* __restrict__ awt_lo, const float* __restrict__ att_v,
    const float* __restrict__ att_b, float* __restrict__ feats) {
  __shared__ __align__(16) float st_s[16][132];
  __shared__ __align__(16) short ah_s[16][132];
  __shared__ __align__(16) short al_s[16][132];
  __shared__ float spart[4][16];
  __shared__ float score_s[16];
  __shared__ float cm[128], cl[128], ca[128];

  int bid = blockIdx.x, tid = threadIdx.x;
  int b, dir, S, featOff; const float* stb;
  if (bid < 256) {
    b = bid >> 1; dir = bid & 1; S = SC_;
    stb = states + (dir ? SZ_ST_CTX : 0) + (size_t)b * SC_ * C_;
    featOff = dir * 128;
  } else {
    int q = bid - 256; b = q >> 1; dir = q & 1; S = SE_;
    stb = states + 2*SZ_ST_CTX + (dir ? SZ_ST_END : 0) + (size_t)b * SE_ * C_;
    featOff = 256 + dir * 128;
  }

  int w = tid >> 6, lane = tid & 63;
  int quad = lane >> 4, l15 = lane & 15;

  // B-frags: wave w covers d = [32w, 32w+32); frag = awt[d][k] (= att_w[k][d])
  int d0 = 32 * w + l15, d1 = d0 + 16;
  bf16x8 bh0[4], bh1[4], bl0[4], bl1[4];
#pragma unroll
  for (int kt = 0; kt < 4; ++kt) {
    bh0[kt] = *(const bf16x8*)&awt_hi[d0*128 + kt*32 + quad*8];
    bh1[kt] = *(const bf16x8*)&awt_hi[d1*128 + kt*32 + quad*8];
    bl0[kt] = *(const bf16x8*)&awt_lo[d0*128 + kt*32 + quad*8];
    bl1[kt] = *(const bf16x8*)&awt_lo[d1*128 + kt*32 + quad*8];
  }
  float vv0 = att_v[d0], vv1 = att_v[d1];
  float bb0 = att_b[d0], bb1 = att_b[d1];

  int c = tid & 127, half = tid >> 7;
  float m = -1e30f, lsum = 0.f, acc = 0.f;

  // chunk staging coords: row = tid>>4, cols (tid&15)*8..+8
  int lrow = tid >> 4, lcol = (tid & 15) * 8;
  float4 p0, p1;
  {
    const float* src = stb + (size_t)lrow * C_ + lcol;
    p0 = *(const float4*)(src);
    p1 = *(const float4*)(src + 4);
  }

  int nchunks = S >> 4;
  for (int ch = 0; ch < nchunks; ++ch) {
    __syncthreads();   // B0: prior chunk's LDS readers done
    float f[8] = {p0.x, p0.y, p0.z, p0.w, p1.x, p1.y, p1.z, p1.w};
    short hi8[8], lo8[8];
#pragma unroll
    for (int j = 0; j < 8; ++j) {
      unsigned short h = f2bf_rne(f[j]);
      float hf = __uint_as_float((unsigned)h << 16);
      hi8[j] = (short)h;
      lo8[j] = (short)f2bf_rne(f[j] - hf);
    }
    *(float4*)(&st_s[lrow][lcol])     = p0;
    *(float4*)(&st_s[lrow][lcol + 4]) = p1;
    *(bf16x8*)(&ah_s[lrow][lcol]) = *(bf16x8*)hi8;
    *(bf16x8*)(&al_s[lrow][lcol]) = *(bf16x8*)lo8;
    if (ch + 1 < nchunks) {   // prefetch next chunk (in flight across compute)
      const float* src = stb + (size_t)((ch + 1) * 16 + lrow) * C_ + lcol;
      p0 = *(const float4*)(src);
      p1 = *(const float4*)(src + 4);
    }
    __syncthreads();   // B1: staging visible

    // T = chunk @ att_w  (bf16x3 MFMA)
    f32x4 ac0 = {0.f, 0.f, 0.f, 0.f}, ac1 = {0.f, 0.f, 0.f, 0.f};
#pragma unroll
    for (int kt = 0; kt < 4; ++kt) {
      bf16x8 a_hi = *(bf16x8*)&ah_s[l15][kt*32 + quad*8];
      bf16x8 a_lo = *(bf16x8*)&al_s[l15][kt*32 + quad*8];
      ac0 = __builtin_amdgcn_mfma_f32_16x16x32_bf16(a_hi, bh0[kt], ac0, 0, 0, 0);
      ac0 = __builtin_amdgcn_mfma_f32_16x16x32_bf16(a_hi, bl0[kt], ac0, 0, 0, 0);
      ac0 = __builtin_amdgcn_mfma_f32_16x16x32_bf16(a_lo, bh0[kt], ac0, 0, 0, 0);
      ac1 = __builtin_amdgcn_mfma_f32_16x16x32_bf16(a_hi, bh1[kt], ac1, 0, 0, 0);
      ac1 = __builtin_amdgcn_mfma_f32_16x16x32_bf16(a_hi, bl1[kt], ac1, 0, 0, 0);
      ac1 = __builtin_amdgcn_mfma_f32_16x16x32_bf16(a_lo, bh1[kt], ac1, 0, 0, 0);
    }

    // epilogue: rows quad*4+r, per-lane d pair -> partial score; quad reduce
    float part[4];
#pragma unroll
    for (int r = 0; r < 4; ++r)
      part[r] = fast_tanh(ac0[r] + bb0) * vv0 + fast_tanh(ac1[r] + bb1) * vv1;
#pragma unroll
    for (int mask = 1; mask <= 8; mask <<= 1)
#pragma unroll
      for (int r = 0; r < 4; ++r)
        part[r] += __shfl_xor(part[r], mask, 64);
    if (l15 == 0) {
#pragma unroll
      for (int r = 0; r < 4; ++r) spart[w][quad*4 + r] = part[r];
    }
    __syncthreads();   // B2: spart visible
    if (tid < 16)
      score_s[tid] = spart[0][tid] + spart[1][tid] + spart[2][tid] + spart[3][tid];
    __syncthreads();   // B3: scores visible

    // online softmax: half processes rows half*8..+8, channel c
    float srow[8]; float smax = m;
#pragma unroll
    for (int r = 0; r < 8; ++r) { srow[r] = score_s[half*8 + r]; smax = fmaxf(smax, srow[r]); }
    float scale = __expf(m - smax);
    acc *= scale; lsum *= scale; m = smax;
#pragma unroll
    for (int r = 0; r < 8; ++r) {
      float wgt = __expf(srow[r] - m);
      lsum += wgt;
      acc += wgt * st_s[half*8 + r][c];
    }
  }

  __syncthreads();
  if (half == 1) { cm[c] = m; cl[c] = lsum; ca[c] = acc; }
  __syncthreads();
  if (half == 0) {
    float m1 = cm[c], l1 = cl[c], a1 = ca[c];
    float M = fmaxf(m, m1);
    float w0 = __expf(m - M), w1 = __expf(m1 - M);
    feats[b * 512 + featOff + c] = (acc * w0 + a1 * w1) / (lsum * w0 + l1 * w1);
  }
}

// ---------------------------------------------------------------------------
// Head
// ---------------------------------------------------------------------------
__global__ __launch_bounds__(128) void head_kernel(
    const float* __restrict__ feats, const float* __restrict__ hid_w,
    const float* __restrict__ hid_b, const float* __restrict__ out_w,
    const float* __restrict__ out_b, float* __restrict__ out) {
  __shared__ __align__(16) float f_s[512];
  __shared__ float part[2];
  int b = blockIdx.x, tid = threadIdx.x;
  for (int i = tid; i < 512; i += 128) f_s[i] = feats[b * 512 + i];
  __syncthreads();
  float h = hid_b[tid];
  for (int k = 0; k < 512; ++k) h += f_s[k] * hid_w[k * 128 + tid];
  h = fmaxf(h, 0.f);
  float p = h * out_w[tid];
#pragma unroll
  for (int off = 32; off > 0; off >>= 1) p += __shfl_xor(p, off, 64);
  if ((tid & 63) == 0) part[tid >> 6] = p;
  __syncthreads();
  if (tid == 0) out[b] = part[0] + part[1] + out_b[0];
}

// ---------------------------------------------------------------------------
extern "C" void kernel_launch(void* const* d_in, const int* in_sizes, int n_in,
                              void* d_out, int out_size, void* d_ws, size_t ws_size,
                              hipStream_t stream) {
  const int*   ctx     = (const int*)d_in[0];
  const int*   endseq  = (const int*)d_in[1];
  const int*   ctx_len = (const int*)d_in[2];
  const int*   end_len = (const int*)d_in[3];
  const float* emb     = (const float*)d_in[4];
  const float* fw_gw   = (const float*)d_in[5];
  const float* fw_gb   = (const float*)d_in[6];
  const float* fw_cw   = (const float*)d_in[7];
  const float* fw_cb   = (const float*)d_in[8];
  const float* bw_gw   = (const float*)d_in[9];
  const float* bw_gb   = (const float*)d_in[10];
  const float* bw_cw   = (const float*)d_in[11];
  const float* bw_cb   = (const float*)d_in[12];
  const float* att_v   = (const float*)d_in[13];
  const float* att_w   = (const float*)d_in[14];
  const float* att_b   = (const float*)d_in[15];
  const float* hid_w   = (const float*)d_in[16];
  const float* hid_b   = (const float*)d_in[17];
  const float* out_w   = (const float*)d_in[18];
  const float* out_b   = (const float*)d_in[19];
  float* ws  = (float*)d_ws;
  float* out = (float*)d_out;

  short* Ahi    = (short*)(ws + OFF_ST);
  short* Alo    = Ahi + (size_t)V_ * KP;
  short* Bthi   = (short*)(ws + OFF_BT);
  short* Btlo   = Bthi + (size_t)NCOL * KP;
  short* awt_hi = (short*)(ws + OFF_AWT);
  short* awt_lo = awt_hi + 128 * 128;

  pack_kernel<<<1299, 256, 0, stream>>>(fw_gw, fw_gb, fw_cw, fw_cb,
                                        bw_gw, bw_gb, bw_cw, bw_cb, ws);
  pack_bt<<<(NCOL * KP + 128 * 128 + 255) / 256, 256, 0, stream>>>(
      ws + OFF_WXP, Bthi, Btlo, att_w, awt_hi, awt_lo);
  pack_emb<<<(int)(((size_t)V_ * KP + 255) / 256), 256, 0, stream>>>(emb, Ahi, Alo);

  dim3 ggrid(6, 391);
  gemm_mfma<<<ggrid, 256, 0, stream>>>(Ahi, Alo, Bthi, Btlo, ws + OFF_PROJ);

  recur_kernel<<<512, 256, 0, stream>>>(ctx, endseq, ctx_len, end_len,
                                        ws + OFF_PROJ, ws + OFF_UALL,
                                        ws + OFF_BIAS, ws + OFF_ST);

  attn_kernel<<<512, 256, 0, stream>>>(ws + OFF_ST, awt_hi, awt_lo,
                                       att_v, att_b, ws + OFF_FEATS);

  head_kernel<<<128, 128, 0, stream>>>(ws + OFF_FEATS, hid_w, hid_b,
                                       out_w, out_b, out);
}